// Round 10
// baseline (706.258 us; speedup 1.0000x reference)
//
#include <hip/hip_runtime.h>
#include <hip/hip_bf16.h>

#define T_STEPS 2048
#define BATCH 16
#define DIM 1024
#define EPSV 1e-6f
#define INVD (1.0f / 1024.0f)
#define SLOTF (BATCH * DIM)      // floats per [B][D] slot
#define SLOT4C (BATCH * DIM / 4) // float4 per slot

typedef short short8 __attribute__((ext_vector_type(8)));
typedef float f32x4 __attribute__((ext_vector_type(4)));

struct alignas(16) bf16x8pack { __hip_bfloat16 v[8]; };

__device__ __forceinline__ float dot4(const float4& a, const float4& c) {
  return fmaf(a.x, c.x, fmaf(a.y, c.y, fmaf(a.z, c.z, a.w * c.w)));
}
__device__ __forceinline__ float fast_rsq(float x) {
  float r;
  asm("v_rsq_f32 %0, %1" : "=v"(r) : "v"(x));
  return r;
}

// ---------------- fp32 -> bf16 convert (vectorized) ----------------
__global__ __launch_bounds__(256) void cvt_kernel(const float* __restrict__ src,
                                                  bf16x8pack* __restrict__ dst, int n8) {
  int i = blockIdx.x * blockDim.x + threadIdx.x;
  if (i >= n8) return;
  const float4* s4 = (const float4*)src + (size_t)i * 2;
  float4 a = s4[0];
  float4 b = s4[1];
  bf16x8pack p;
  p.v[0] = __float2bfloat16(a.x); p.v[1] = __float2bfloat16(a.y);
  p.v[2] = __float2bfloat16(a.z); p.v[3] = __float2bfloat16(a.w);
  p.v[4] = __float2bfloat16(b.x); p.v[5] = __float2bfloat16(b.y);
  p.v[6] = __float2bfloat16(b.z); p.v[7] = __float2bfloat16(b.w);
  dst[i] = p;
}

// ---------------- bf16 MFMA GEMM: out[m][e] = alpha*(sum_d X[m][d]*W[e][d] + b[e]) ----
__global__ __launch_bounds__(256) void gemm_kernel(
    const __hip_bfloat16* __restrict__ Xb,
    const __hip_bfloat16* __restrict__ Wb,
    const float* __restrict__ bias,
    const float* __restrict__ log_alpha_p,
    float* __restrict__ hreg) {
  __shared__ __hip_bfloat16 As[128 * 32];
  __shared__ __hip_bfloat16 Bs[128 * 32];
  const int tid = threadIdx.x;
  const int wave = tid >> 6, lane = tid & 63;
  const int m0 = blockIdx.y * 128;
  const int e0 = blockIdx.x * 128;
  const int wm = (wave >> 1) * 64;
  const int wn = (wave & 1) * 64;
  const int l15 = lane & 15, l4 = lane >> 4;

  f32x4 acc[4][4] = {};

  const int srow = wave * 16 + (lane >> 2);
  const int sch = (lane & 3) * 8;

  for (int kt = 0; kt < DIM; kt += 32) {
    __syncthreads();
#pragma unroll
    for (int i = 0; i < 2; ++i) {
      const __hip_bfloat16* ga = Xb + (size_t)(m0 + i * 64 + srow) * DIM + kt + sch;
      const __hip_bfloat16* gb = Wb + (size_t)(e0 + i * 64 + srow) * DIM + kt + sch;
      __builtin_amdgcn_global_load_lds(
          (const __attribute__((address_space(1))) void*)ga,
          (__attribute__((address_space(3))) void*)((char*)As + (i * 64 + wave * 16) * 64),
          16, 0, 0);
      __builtin_amdgcn_global_load_lds(
          (const __attribute__((address_space(1))) void*)gb,
          (__attribute__((address_space(3))) void*)((char*)Bs + (i * 64 + wave * 16) * 64),
          16, 0, 0);
    }
    __syncthreads();
    short8 a[4], b[4];
#pragma unroll
    for (int f = 0; f < 4; ++f)
      a[f] = *(const short8*)((const char*)As + ((wm + f * 16 + l15) * 32 + l4 * 8) * 2);
#pragma unroll
    for (int g = 0; g < 4; ++g)
      b[g] = *(const short8*)((const char*)Bs + ((wn + g * 16 + l15) * 32 + l4 * 8) * 2);
#pragma unroll
    for (int f = 0; f < 4; ++f)
#pragma unroll
      for (int g = 0; g < 4; ++g)
        acc[f][g] = __builtin_amdgcn_mfma_f32_16x16x32_bf16(a[f], b[g], acc[f][g], 0, 0, 0);
  }
  const float alpha = __expf(log_alpha_p[0]);
#pragma unroll
  for (int g = 0; g < 4; ++g) {
    const int e = e0 + wn + g * 16 + l15;
    const float bv = bias[e];
#pragma unroll
    for (int f = 0; f < 4; ++f) {
#pragma unroll
      for (int r = 0; r < 4; ++r) {
        const int m = m0 + wm + f * 16 + l4 * 4 + r;
        hreg[(size_t)(m + BATCH) * DIM + e] = alpha * (acc[f][g][r] + bv);
      }
    }
  }
}

// ---------------- DPP wave-sum helper (total lands in lane 63) ----------------
__device__ __forceinline__ float dpp_sum_reg(float x) {
  float acc = x;
#define DPP_ADD(ctrl)                                                              \
  {                                                                                \
    int t_ = __builtin_amdgcn_update_dpp(0, __float_as_int(acc), (ctrl), 0xf, 0xf, \
                                         true);                                    \
    acc += __int_as_float(t_);                                                     \
  }
  DPP_ADD(0x111); DPP_ADD(0x112); DPP_ADD(0x114); DPP_ADD(0x118);
  DPP_ADD(0x142); DPP_ADD(0x143);
#undef DPP_ADD
  return acc;
}

// ---- precompute: scal4[t]=(e, 2d, 2d2, 2d3), d45[t]=(2d4, 2d5)  (dk = W_{t-k}.W_t) ----
__global__ __launch_bounds__(64) void dots_kernel(const float* __restrict__ hreg,
                                                  float4* __restrict__ scal4,
                                                  float2* __restrict__ d45g) {
  const int t = blockIdx.x >> 4;
  const int b = blockIdx.x & 15;
  const int lane = threadIdx.x;
  const float4* w  = (const float4*)(hreg + (size_t)(t + 1) * SLOTF + b * DIM);
  const float4* m1 = (const float4*)(hreg + (size_t)(t    ) * SLOTF + b * DIM);
  const float4* m2 = (const float4*)(hreg + (size_t)(t - 1) * SLOTF + b * DIM);
  const float4* m3 = (const float4*)(hreg + (size_t)(t - 2) * SLOTF + b * DIM);
  const float4* m4 = (const float4*)(hreg + (size_t)(t - 3) * SLOTF + b * DIM);
  const float4* m5 = (const float4*)(hreg + (size_t)(t - 4) * SLOTF + b * DIM);
  float e = 0.f, d = 0.f, d2 = 0.f, d3 = 0.f, d4 = 0.f, d5 = 0.f;
#pragma unroll
  for (int j = 0; j < 4; ++j) {
    float4 a = w[lane + 64 * j];
    e = fmaf(a.x, a.x, fmaf(a.y, a.y, fmaf(a.z, a.z, fmaf(a.w, a.w, e))));
    if (t >= 1) { float4 p = m1[lane + 64 * j];
      d = fmaf(p.x, a.x, fmaf(p.y, a.y, fmaf(p.z, a.z, fmaf(p.w, a.w, d)))); }
    if (t >= 2) { float4 p = m2[lane + 64 * j];
      d2 = fmaf(p.x, a.x, fmaf(p.y, a.y, fmaf(p.z, a.z, fmaf(p.w, a.w, d2)))); }
    if (t >= 3) { float4 p = m3[lane + 64 * j];
      d3 = fmaf(p.x, a.x, fmaf(p.y, a.y, fmaf(p.z, a.z, fmaf(p.w, a.w, d3)))); }
    if (t >= 4) { float4 p = m4[lane + 64 * j];
      d4 = fmaf(p.x, a.x, fmaf(p.y, a.y, fmaf(p.z, a.z, fmaf(p.w, a.w, d4)))); }
    if (t >= 5) { float4 p = m5[lane + 64 * j];
      d5 = fmaf(p.x, a.x, fmaf(p.y, a.y, fmaf(p.z, a.z, fmaf(p.w, a.w, d5)))); }
  }
  e = dpp_sum_reg(e);
  d = dpp_sum_reg(d);
  d2 = dpp_sum_reg(d2);
  d3 = dpp_sum_reg(d3);
  d4 = dpp_sum_reg(d4);
  d5 = dpp_sum_reg(d5);
  if (lane == 63) {
    scal4[b * T_STEPS + t] = make_float4(e, d + d, d2 + d2, d3 + d3);
    d45g[b * T_STEPS + t] = make_float2(d4 + d4, d5 + d5);
  }
}

// ---------------- scan: r7 4-wave structure + LDS W-ring via global_load_lds ------
// W rows staged into a 12-slot LDS ring by global_load_lds (no VGPR dest -> the
// compiler CANNOT sink the prefetch; rounds 3-9 proved VGPR rings always sink).
// Each wave's gl_lds writes its own quarter; thread tid reads its own 16B ->
// W staging needs NO barriers, only per-wave counted vmcnt(22):
//   W_{i+6} (G-operand, tightest) was issued at step i-6 with 2 same-step +
//   5*4 younger vm ops -> wait-until-<=22 confirms it. Never drain in-loop.
// LDS->reg prefetch 1 step ahead (full-step slack over ~120cy DS latency).
// Gp cross-wave pipeline + lgkmcnt(3) + barrier/2-steps byte-for-byte from r7.
__global__ __launch_bounds__(256, 1) void scan_kernel(
    const float* __restrict__ h0,
    const float4* __restrict__ scal4,
    const float2* __restrict__ d45g,
    float* __restrict__ hreg) {
  const int b = blockIdx.x;
  const int tid = threadIdx.x;
  const int wave = tid >> 6;
  const int lane = tid & 63;
  float4* h4 = (float4*)hreg;
  const int idx4 = b * 256 + tid;

  __shared__ float4 ldsW[12 * 256];        // 48 KB: 12-slot W ring, 4KB/slot
  __shared__ alignas(16) float Gp[4][4];   // [target&3][wave]
  __shared__ float initP[4][6];

#define GLD(SLOT, WIDX)                                                            \
  __builtin_amdgcn_global_load_lds(                                                \
      (const __attribute__((address_space(1))) void*)(hreg +                       \
          (size_t)SLOTF * ((WIDX) + 1) + (size_t)idx4 * 4),                        \
      (__attribute__((address_space(3))) void*)((char*)ldsW + (SLOT) * 4096 +      \
                                                wave * 1024),                      \
      16, 0, 0)

  const float4* scg = scal4 + b * T_STEPS;
  const float2* dg = d45g + b * T_STEPS;

  // ---- prologue: stage W_0..W_11, load h0 + scalar startup values, drain
  GLD(0, 0); GLD(1, 1); GLD(2, 2); GLD(3, 3); GLD(4, 4); GLD(5, 5);
  GLD(6, 6); GLD(7, 7); GLD(8, 8); GLD(9, 9); GLD(10, 10); GLD(11, 11);
  float4 h0v = ((const float4*)h0)[idx4];
  const float e1 = scg[1].x;
  float4 sc2v = scg[2], sc3v = scg[3], sc4v = scg[4], sc5v = scg[5];
  const float D45x = dg[5].x;
  // steady scal rings: sc{k}_ holds scal[i] for first steady i with i&3==k
  float4 sc0_ = scg[8], sc1_ = scg[9], sc2_ = scg[6], sc3_ = scg[7];
  float2 d0_ = dg[8], d1_ = dg[9], d2_ = dg[6], d3_ = dg[7];
  asm volatile("s_waitcnt vmcnt(0)" ::: "memory");

  // own-quarter LDS reads (no barrier needed: each wave reads what it staged)
  float4 w0v = ldsW[0 * 256 + tid];
  float4 w1v = ldsW[1 * 256 + tid];
  float4 t2 = ldsW[2 * 256 + tid];
  float4 t3 = ldsW[3 * 256 + tid];
  float4 t4 = ldsW[4 * 256 + tid];
  float4 t5 = ldsW[5 * 256 + tid];

  h4[idx4] = h0v;  // slot 0 = h_0
  float4 s;
  s.x = h0v.x + w0v.x; s.y = h0v.y + w0v.y;
  s.z = h0v.z + w0v.z; s.w = h0v.w + w0v.w;

  // startup cross-wave dots via initP (r7)
  {
    float q  = dpp_sum_reg(dot4(s, s));
    float r  = dpp_sum_reg(dot4(s, w1v));
    float c2 = dpp_sum_reg(dot4(s, t2));
    float c3 = dpp_sum_reg(dot4(s, t3));
    float c4 = dpp_sum_reg(dot4(s, t4));
    float c5 = dpp_sum_reg(dot4(s, t5));
    if (lane == 63) {
      initP[wave][0] = q;  initP[wave][1] = r;  initP[wave][2] = c2;
      initP[wave][3] = c3; initP[wave][4] = c4; initP[wave][5] = c5;
    }
  }
  __syncthreads();
  const float n1 = (initP[0][0] + initP[1][0]) + (initP[2][0] + initP[3][0]);
  float t1s = (initP[0][1] + initP[1][1]) + (initP[2][1] + initP[3][1]);
  float t2s = (initP[0][2] + initP[1][2]) + (initP[2][2] + initP[3][2]);
  float t3s = (initP[0][3] + initP[1][3]) + (initP[2][3] + initP[3][3]);
  float t4s = (initP[0][4] + initP[1][4]) + (initP[2][4] + initP[3][4]);
  float t5s = (initP[0][5] + initP[1][5]) + (initP[2][5] + initP[3][5]);
  const float B1 = t1s + t1s, C2 = t2s + t2s, C3 = t3s + t3s,
              C4 = t4s + t4s, C5 = t5s + t5s;
  GLD(0, 12);  // slot 0 freed (w0v consumed) -> W_12

  float n = n1, rm1, rm2, rm3, rm4, pp;
  float gr0 = 0.f, gr1 = 0.f;
  float4 rv = make_float4(0.f, 0.f, 0.f, 0.f);
  float4 hvE, hvO, wSa, wSb, wGa, wGb;

#define BAR0 { asm volatile("s_waitcnt lgkmcnt(0)" ::: "memory"); __builtin_amdgcn_s_barrier(); }

  // ---- peel steps 1..5 (r7 pipeline; W from LDS ring)
  {  // step 1 (odd)
    const float rinv = fast_rsq(fmaf(n, INVD, EPSV));
    n = fmaf(rinv, fmaf(rinv, n, B1), e1);
    hvO.x = rinv * s.x; hvO.y = rinv * s.y; hvO.z = rinv * s.z; hvO.w = rinv * s.w;
    h4[(size_t)SLOT4C * 1 + idx4] = hvO;
    s.x = hvO.x + w1v.x; s.y = hvO.y + w1v.y; s.z = hvO.z + w1v.z; s.w = hvO.w + w1v.w;
    float4 wg = ldsW[6 * 256 + tid];           // W_6
    pp = dpp_sum_reg(dot4(hvO, wg));           // G_6 partial
    GLD(1, 13);
    rm1 = rinv;
    BAR0
  }
  {  // step 2
    if (lane == 63) Gp[2][wave] = pp;          // target 6
    const float rinv = fast_rsq(fmaf(n, INVD, EPSV));
    const float BB = fmaf(rm1, C2, sc2v.y);
    n = fmaf(rinv, fmaf(rinv, n, BB), sc2v.x);
    hvE.x = rinv * s.x; hvE.y = rinv * s.y; hvE.z = rinv * s.z; hvE.w = rinv * s.w;
    h4[(size_t)SLOT4C * 2 + idx4] = hvE;
    s.x = hvE.x + t2.x; s.y = hvE.y + t2.y; s.z = hvE.z + t2.z; s.w = hvE.w + t2.w;
    float4 wg = ldsW[7 * 256 + tid];           // W_7
    pp = dpp_sum_reg(dot4(hvE, wg));           // G_7 partial
    GLD(2, 14);
    rm2 = rm1; rm1 = rinv;
    BAR0
  }
  {  // step 3
    if (lane == 63) Gp[3][wave] = pp;          // target 7
    const float rinv = fast_rsq(fmaf(n, INVD, EPSV));
    const float BB = fmaf(rm1, fmaf(rm2, C3, sc3v.z), sc3v.y);
    n = fmaf(rinv, fmaf(rinv, n, BB), sc3v.x);
    hvO.x = rinv * s.x; hvO.y = rinv * s.y; hvO.z = rinv * s.z; hvO.w = rinv * s.w;
    h4[(size_t)SLOT4C * 3 + idx4] = hvO;
    s.x = hvO.x + t3.x; s.y = hvO.y + t3.y; s.z = hvO.z + t3.z; s.w = hvO.w + t3.w;
    float4 wg = ldsW[8 * 256 + tid];           // W_8
    pp = dpp_sum_reg(dot4(hvO, wg));           // G_8 partial
    GLD(3, 15);
    rm3 = rm2; rm2 = rm1; rm1 = rinv;
    BAR0
  }
  {  // step 4
    if (lane == 63) Gp[0][wave] = pp;          // target 8
    const float rinv = fast_rsq(fmaf(n, INVD, EPSV));
    const float BB = fmaf(rm1, fmaf(rm2, fmaf(rm3, C4, sc4v.w), sc4v.z), sc4v.y);
    n = fmaf(rinv, fmaf(rinv, n, BB), sc4v.x);
    rv = *(const float4*)&Gp[2][0];            // target-6 partials
    hvE.x = rinv * s.x; hvE.y = rinv * s.y; hvE.z = rinv * s.z; hvE.w = rinv * s.w;
    h4[(size_t)SLOT4C * 4 + idx4] = hvE;
    s.x = hvE.x + t4.x; s.y = hvE.y + t4.y; s.z = hvE.z + t4.z; s.w = hvE.w + t4.w;
    float4 wg = ldsW[9 * 256 + tid];           // W_9
    pp = dpp_sum_reg(dot4(hvE, wg));           // G_9 partial
    GLD(4, 16);
    rm4 = rm3; rm3 = rm2; rm2 = rm1; rm1 = rinv;
    BAR0
  }
  {  // step 5
    if (lane == 63) Gp[1][wave] = pp;          // target 9
    const float rinv = fast_rsq(fmaf(n, INVD, EPSV));
    const float BB =
        fmaf(rm1, fmaf(rm2, fmaf(rm3, fmaf(rm4, C5, D45x), sc5v.w), sc5v.z), sc5v.y);
    n = fmaf(rinv, fmaf(rinv, n, BB), sc5v.x);
    { float gt = (rv.x + rv.y) + (rv.z + rv.w); gr0 = gt + gt; }  // 2*G_6
    rv = *(const float4*)&Gp[3][0];            // target-7 partials
    hvO.x = rinv * s.x; hvO.y = rinv * s.y; hvO.z = rinv * s.z; hvO.w = rinv * s.w;
    h4[(size_t)SLOT4C * 5 + idx4] = hvO;
    s.x = hvO.x + t5.x; s.y = hvO.y + t5.y; s.z = hvO.z + t5.z; s.w = hvO.w + t5.w;
    float4 wg = ldsW[10 * 256 + tid];          // W_10
    pp = dpp_sum_reg(dot4(hvO, wg));           // G_10 partial
    GLD(5, 17);
    wSa = ldsW[6 * 256 + tid];                 // W_6  (step-6 s-update)
    wGa = ldsW[11 * 256 + tid];                // W_11 (step-6 G-operand)
    rm4 = rm3; rm3 = rm2; rm2 = rm1; rm1 = rinv;
    BAR0
  }
  asm volatile("s_waitcnt vmcnt(0)" ::: "memory");  // one-time drain before steady

// Steady step i>=6. DS order: [Gpw, rv, WPread, WGPread] -> lgkmcnt(3)@barrier
// confirms Gpw (r7-proven). vmcnt(22) orders gl_lds->ds_read (see header).
#define STEP(I_, SLW, SLG, SLP, GW, GR, SC, D45, GRU, GRW, WU, WGU, WP, WGP, HV, BAR_) \
  {                                                                                  \
    const int i_ = (I_);                                                             \
    asm volatile("s_waitcnt vmcnt(22)" ::: "memory");                                \
    if (lane == 63) Gp[GW][wave] = pp;                                               \
    { float gt_ = (rv.x + rv.y) + (rv.z + rv.w); GRW = gt_ + gt_; }                  \
    rv = *(const float4*)&Gp[GR][0];                                                 \
    WP = ldsW[(SLW) * 256 + tid];                                                    \
    WGP = ldsW[(SLG) * 256 + tid];                                                   \
    const float rinv = fast_rsq(fmaf(n, INVD, EPSV));                                \
    const float BB = fmaf(                                                           \
        rm1, fmaf(rm2, fmaf(rm3, fmaf(rm4, (D45).y + (GRU), (D45).x), (SC).w),       \
                  (SC).z), (SC).y);                                                  \
    n = fmaf(rinv, fmaf(rinv, n, BB), (SC).x);                                       \
    HV.x = rinv * s.x; HV.y = rinv * s.y; HV.z = rinv * s.z; HV.w = rinv * s.w;      \
    h4[(size_t)SLOT4C * i_ + idx4] = HV;                                             \
    s.x = HV.x + WU.x; s.y = HV.y + WU.y; s.z = HV.z + WU.z; s.w = HV.w + WU.w;      \
    pp = dpp_sum_reg(dot4(HV, WGU));                                                 \
    { const int wsrc_ = (i_ + 12 <= 2047) ? (i_ + 12) : 2047; GLD(SLP, wsrc_); }     \
    { const int isc_ = (i_ + 4 <= 2047) ? (i_ + 4) : 2047;                           \
      SC = scg[isc_]; D45 = dg[isc_]; }                                              \
    rm4 = rm3; rm3 = rm2; rm2 = rm1; rm1 = rinv;                                     \
    if (BAR_) { asm volatile("s_waitcnt lgkmcnt(3)" ::: "memory");                   \
                __builtin_amdgcn_s_barrier(); }                                      \
  }

  // main loop: i = 6..2045 in chunks of 12 (ii ≡ 6 mod 12)
  for (int ii = 6; ii <= 2034; ii += 12) {
    STEP(ii + 0,  7,  0,  6, 2, 0, sc2_, d2_, gr0, gr1, wSa, wGa, wSb, wGb, hvE, 0)
    STEP(ii + 1,  8,  1,  7, 3, 1, sc3_, d3_, gr1, gr0, wSb, wGb, wSa, wGa, hvO, 1)
    STEP(ii + 2,  9,  2,  8, 0, 2, sc0_, d0_, gr0, gr1, wSa, wGa, wSb, wGb, hvE, 0)
    STEP(ii + 3, 10,  3,  9, 1, 3, sc1_, d1_, gr1, gr0, wSb, wGb, wSa, wGa, hvO, 1)
    STEP(ii + 4, 11,  4, 10, 2, 0, sc2_, d2_, gr0, gr1, wSa, wGa, wSb, wGb, hvE, 0)
    STEP(ii + 5,  0,  5, 11, 3, 1, sc3_, d3_, gr1, gr0, wSb, wGb, wSa, wGa, hvO, 1)
    STEP(ii + 6,  1,  6,  0, 0, 2, sc0_, d0_, gr0, gr1, wSa, wGa, wSb, wGb, hvE, 0)
    STEP(ii + 7,  2,  7,  1, 1, 3, sc1_, d1_, gr1, gr0, wSb, wGb, wSa, wGa, hvO, 1)
    STEP(ii + 8,  3,  8,  2, 2, 0, sc2_, d2_, gr0, gr1, wSa, wGa, wSb, wGb, hvE, 0)
    STEP(ii + 9,  4,  9,  3, 3, 1, sc3_, d3_, gr1, gr0, wSb, wGb, wSa, wGa, hvO, 1)
    STEP(ii + 10, 5, 10,  4, 0, 2, sc0_, d0_, gr0, gr1, wSa, wGa, wSb, wGb, hvE, 0)
    STEP(ii + 11, 6, 11,  5, 1, 3, sc1_, d1_, gr1, gr0, wSb, wGb, wSa, wGa, hvO, 1)
  }
  // tail: i = 2046 (≡6 mod 12), 2047 (≡7)
  STEP(2046, 7, 0, 6, 2, 0, sc2_, d2_, gr0, gr1, wSa, wGa, wSb, wGb, hvE, 0)
  STEP(2047, 8, 1, 7, 3, 1, sc3_, d3_, gr1, gr0, wSb, wGb, wSa, wGa, hvO, 1)
#undef STEP
#undef BAR0
#undef GLD

  // final: h_2048 = rinv * s -> slot 2048
  const float rinvT = fast_rsq(fmaf(n, INVD, EPSV));
  float4 o;
  o.x = rinvT * s.x; o.y = rinvT * s.y; o.z = rinvT * s.z; o.w = rinvT * s.w;
  h4[(size_t)SLOT4C * T_STEPS + idx4] = o;
}

// ---------------- outs[t] = h_{t+1} * silu(h_{t+1}) ----------------
__global__ __launch_bounds__(256) void silu_kernel(const float4* __restrict__ hsrc,
                                                   float4* __restrict__ out4, int n4) {
  int i = blockIdx.x * blockDim.x + threadIdx.x;
  if (i >= n4) return;
  float4 h = hsrc[i];
  float4 o;
  o.x = h.x * h.x / (1.f + __expf(-h.x));
  o.y = h.y * h.y / (1.f + __expf(-h.y));
  o.z = h.z * h.z / (1.f + __expf(-h.z));
  o.w = h.w * h.w / (1.f + __expf(-h.w));
  out4[i] = o;
}

extern "C" void kernel_launch(void* const* d_in, const int* in_sizes, int n_in,
                              void* d_out, int out_size, void* d_ws, size_t ws_size,
                              hipStream_t stream) {
  (void)in_sizes; (void)n_in; (void)d_ws; (void)ws_size; (void)out_size;
  const float* x = (const float*)d_in[0];
  const float* h0 = (const float*)d_in[1];
  const float* W = (const float*)d_in[2];
  const float* bias = (const float*)d_in[3];
  const float* log_alpha = (const float*)d_in[4];

  float* out = (float*)d_out;                               // outs region [T][B][D]
  float* hreg = out + (size_t)T_STEPS * BATCH * DIM;        // h region [T+1][B][D]
  // staging overlays the outs region (consumed before scan/silu touch it)
  __hip_bfloat16* xb = (__hip_bfloat16*)d_out;
  __hip_bfloat16* wb = (__hip_bfloat16*)((char*)d_out + (size_t)T_STEPS * BATCH * DIM * 2);
  float4* scal4 = (float4*)(out + (size_t)26 * 1024 * 1024);  // 104 MB offset
  float2* d45g = (float2*)(out + (size_t)27 * 1024 * 1024);   // 108 MB offset

  const int nx8 = T_STEPS * BATCH * DIM / 8;
  const int nw8 = DIM * DIM / 8;
  cvt_kernel<<<nx8 / 256, 256, 0, stream>>>(x, (bf16x8pack*)xb, nx8);
  cvt_kernel<<<nw8 / 256, 256, 0, stream>>>(W, (bf16x8pack*)wb, nw8);

  dim3 ggrid(DIM / 128, (T_STEPS * BATCH) / 128);
  gemm_kernel<<<ggrid, 256, 0, stream>>>(xb, wb, bias, log_alpha, hreg);

  dots_kernel<<<T_STEPS * BATCH, 64, 0, stream>>>(hreg, scal4, d45g);

  scan_kernel<<<BATCH, 256, 0, stream>>>(h0, scal4, d45g, hreg);

  const int n4 = T_STEPS * BATCH * DIM / 4;
  silu_kernel<<<n4 / 256, 256, 0, stream>>>((const float4*)(hreg + BATCH * DIM),
                                            (float4*)out, n4);
}

// Round 11
// 691.538 us; speedup vs baseline: 1.0213x; 1.0213x over previous
//
#include <hip/hip_runtime.h>
#include <hip/hip_bf16.h>

#define T_STEPS 2048
#define BATCH 16
#define DIM 1024
#define EPSV 1e-6f
#define INVD (1.0f / 1024.0f)
#define SLOTF (BATCH * DIM)      // floats per [B][D] slot
#define SLOT4C (BATCH * DIM / 4) // float4 per slot

typedef short short8 __attribute__((ext_vector_type(8)));
typedef float f32x4 __attribute__((ext_vector_type(4)));

struct alignas(16) bf16x8pack { __hip_bfloat16 v[8]; };

__device__ __forceinline__ float dot4(const float4& a, const float4& c) {
  return fmaf(a.x, c.x, fmaf(a.y, c.y, fmaf(a.z, c.z, a.w * c.w)));
}
__device__ __forceinline__ float fast_rsq(float x) {
  float r;
  asm("v_rsq_f32 %0, %1" : "=v"(r) : "v"(x));
  return r;
}

// ---------------- fp32 -> bf16 convert (vectorized) ----------------
__global__ __launch_bounds__(256) void cvt_kernel(const float* __restrict__ src,
                                                  bf16x8pack* __restrict__ dst, int n8) {
  int i = blockIdx.x * blockDim.x + threadIdx.x;
  if (i >= n8) return;
  const float4* s4 = (const float4*)src + (size_t)i * 2;
  float4 a = s4[0];
  float4 b = s4[1];
  bf16x8pack p;
  p.v[0] = __float2bfloat16(a.x); p.v[1] = __float2bfloat16(a.y);
  p.v[2] = __float2bfloat16(a.z); p.v[3] = __float2bfloat16(a.w);
  p.v[4] = __float2bfloat16(b.x); p.v[5] = __float2bfloat16(b.y);
  p.v[6] = __float2bfloat16(b.z); p.v[7] = __float2bfloat16(b.w);
  dst[i] = p;
}

// ---------------- bf16 MFMA GEMM: out[m][e] = alpha*(sum_d X[m][d]*W[e][d] + b[e]) ----
__global__ __launch_bounds__(256) void gemm_kernel(
    const __hip_bfloat16* __restrict__ Xb,
    const __hip_bfloat16* __restrict__ Wb,
    const float* __restrict__ bias,
    const float* __restrict__ log_alpha_p,
    float* __restrict__ hreg) {
  __shared__ __hip_bfloat16 As[128 * 32];
  __shared__ __hip_bfloat16 Bs[128 * 32];
  const int tid = threadIdx.x;
  const int wave = tid >> 6, lane = tid & 63;
  const int m0 = blockIdx.y * 128;
  const int e0 = blockIdx.x * 128;
  const int wm = (wave >> 1) * 64;
  const int wn = (wave & 1) * 64;
  const int l15 = lane & 15, l4 = lane >> 4;

  f32x4 acc[4][4] = {};

  const int srow = wave * 16 + (lane >> 2);
  const int sch = (lane & 3) * 8;

  for (int kt = 0; kt < DIM; kt += 32) {
    __syncthreads();
#pragma unroll
    for (int i = 0; i < 2; ++i) {
      const __hip_bfloat16* ga = Xb + (size_t)(m0 + i * 64 + srow) * DIM + kt + sch;
      const __hip_bfloat16* gb = Wb + (size_t)(e0 + i * 64 + srow) * DIM + kt + sch;
      __builtin_amdgcn_global_load_lds(
          (const __attribute__((address_space(1))) void*)ga,
          (__attribute__((address_space(3))) void*)((char*)As + (i * 64 + wave * 16) * 64),
          16, 0, 0);
      __builtin_amdgcn_global_load_lds(
          (const __attribute__((address_space(1))) void*)gb,
          (__attribute__((address_space(3))) void*)((char*)Bs + (i * 64 + wave * 16) * 64),
          16, 0, 0);
    }
    __syncthreads();
    short8 a[4], b[4];
#pragma unroll
    for (int f = 0; f < 4; ++f)
      a[f] = *(const short8*)((const char*)As + ((wm + f * 16 + l15) * 32 + l4 * 8) * 2);
#pragma unroll
    for (int g = 0; g < 4; ++g)
      b[g] = *(const short8*)((const char*)Bs + ((wn + g * 16 + l15) * 32 + l4 * 8) * 2);
#pragma unroll
    for (int f = 0; f < 4; ++f)
#pragma unroll
      for (int g = 0; g < 4; ++g)
        acc[f][g] = __builtin_amdgcn_mfma_f32_16x16x32_bf16(a[f], b[g], acc[f][g], 0, 0, 0);
  }
  const float alpha = __expf(log_alpha_p[0]);
#pragma unroll
  for (int g = 0; g < 4; ++g) {
    const int e = e0 + wn + g * 16 + l15;
    const float bv = bias[e];
#pragma unroll
    for (int f = 0; f < 4; ++f) {
#pragma unroll
      for (int r = 0; r < 4; ++r) {
        const int m = m0 + wm + f * 16 + l4 * 4 + r;
        hreg[(size_t)(m + BATCH) * DIM + e] = alpha * (acc[f][g][r] + bv);
      }
    }
  }
}

// ---------------- DPP wave-sum helper (total lands in lane 63) ----------------
__device__ __forceinline__ float dpp_sum_reg(float x) {
  float acc = x;
#define DPP_ADD(ctrl)                                                              \
  {                                                                                \
    int t_ = __builtin_amdgcn_update_dpp(0, __float_as_int(acc), (ctrl), 0xf, 0xf, \
                                         true);                                    \
    acc += __int_as_float(t_);                                                     \
  }
  DPP_ADD(0x111); DPP_ADD(0x112); DPP_ADD(0x114); DPP_ADD(0x118);
  DPP_ADD(0x142); DPP_ADD(0x143);
#undef DPP_ADD
  return acc;
}

// ---- precompute: scal4[t]=(e, 2d, 2d2, 2d3), d45[t]=(2d4, 2d5)  (dk = W_{t-k}.W_t) ----
__global__ __launch_bounds__(64) void dots_kernel(const float* __restrict__ hreg,
                                                  float4* __restrict__ scal4,
                                                  float2* __restrict__ d45g) {
  const int t = blockIdx.x >> 4;
  const int b = blockIdx.x & 15;
  const int lane = threadIdx.x;
  const float4* w  = (const float4*)(hreg + (size_t)(t + 1) * SLOTF + b * DIM);
  const float4* m1 = (const float4*)(hreg + (size_t)(t    ) * SLOTF + b * DIM);
  const float4* m2 = (const float4*)(hreg + (size_t)(t - 1) * SLOTF + b * DIM);
  const float4* m3 = (const float4*)(hreg + (size_t)(t - 2) * SLOTF + b * DIM);
  const float4* m4 = (const float4*)(hreg + (size_t)(t - 3) * SLOTF + b * DIM);
  const float4* m5 = (const float4*)(hreg + (size_t)(t - 4) * SLOTF + b * DIM);
  float e = 0.f, d = 0.f, d2 = 0.f, d3 = 0.f, d4 = 0.f, d5 = 0.f;
#pragma unroll
  for (int j = 0; j < 4; ++j) {
    float4 a = w[lane + 64 * j];
    e = fmaf(a.x, a.x, fmaf(a.y, a.y, fmaf(a.z, a.z, fmaf(a.w, a.w, e))));
    if (t >= 1) { float4 p = m1[lane + 64 * j];
      d = fmaf(p.x, a.x, fmaf(p.y, a.y, fmaf(p.z, a.z, fmaf(p.w, a.w, d)))); }
    if (t >= 2) { float4 p = m2[lane + 64 * j];
      d2 = fmaf(p.x, a.x, fmaf(p.y, a.y, fmaf(p.z, a.z, fmaf(p.w, a.w, d2)))); }
    if (t >= 3) { float4 p = m3[lane + 64 * j];
      d3 = fmaf(p.x, a.x, fmaf(p.y, a.y, fmaf(p.z, a.z, fmaf(p.w, a.w, d3)))); }
    if (t >= 4) { float4 p = m4[lane + 64 * j];
      d4 = fmaf(p.x, a.x, fmaf(p.y, a.y, fmaf(p.z, a.z, fmaf(p.w, a.w, d4)))); }
    if (t >= 5) { float4 p = m5[lane + 64 * j];
      d5 = fmaf(p.x, a.x, fmaf(p.y, a.y, fmaf(p.z, a.z, fmaf(p.w, a.w, d5)))); }
  }
  e = dpp_sum_reg(e);
  d = dpp_sum_reg(d);
  d2 = dpp_sum_reg(d2);
  d3 = dpp_sum_reg(d3);
  d4 = dpp_sum_reg(d4);
  d5 = dpp_sum_reg(d5);
  if (lane == 63) {
    scal4[b * T_STEPS + t] = make_float4(e, d + d, d2 + d2, d3 + d3);
    d45g[b * T_STEPS + t] = make_float2(d4 + d4, d5 + d5);
  }
}

// ---------------- scan: r7 base + W via 12-slot LDS ring (global_load_lds) --------
// ONLY change vs r7 (323us): W rows no longer in a (always-sunk) VGPR ring; they
// are staged by global_load_lds into ldsW (compiler cannot sink: no VGPR dest).
// VM ops/step = 2 (h-store, GLD). Tightest ds_read (G-slot, 6-step slack) has
// >=10 younger VM ops -> vmcnt(10) guarantees (in-order vmcnt retirement); free
// in steady state. DS ops/step = 6 -> barrier wait lgkmcnt(5) confirms the Gp
// write even if first-issued. scal/d45 stay in LDS exactly as r7.
__global__ __launch_bounds__(256, 1) void scan_kernel(
    const float* __restrict__ h0,
    const float4* __restrict__ scal4,
    const float2* __restrict__ d45g,
    float* __restrict__ hreg) {
  const int b = blockIdx.x;
  const int tid = threadIdx.x;
  const int wave = tid >> 6;
  const int lane = tid & 63;
  float4* h4 = (float4*)hreg;
  const int idx4 = b * 256 + tid;

  __shared__ float4 ldsW[12 * 256];        // 48 KB: 12-slot W ring, 4KB/slot
  __shared__ float4 scLDS[T_STEPS];        // 32 KB
  __shared__ float2 d45LDS[T_STEPS];       // 16 KB
  __shared__ alignas(16) float Gp[4][4];   // [target&3][wave]
  __shared__ float initP[4][6];

#define GLD(SLOT, WIDX)                                                            \
  __builtin_amdgcn_global_load_lds(                                                \
      (const __attribute__((address_space(1))) void*)(hreg +                       \
          (size_t)SLOTF * ((WIDX) + 1) + (size_t)idx4 * 4),                        \
      (__attribute__((address_space(3))) void*)((char*)ldsW + (SLOT) * 4096 +      \
                                                wave * 1024),                      \
      16, 0, 0)

  // ---- prologue: stage W_0..W_11 (gl_lds), scal/d45 -> LDS, drain
  GLD(0, 0); GLD(1, 1); GLD(2, 2); GLD(3, 3); GLD(4, 4); GLD(5, 5);
  GLD(6, 6); GLD(7, 7); GLD(8, 8); GLD(9, 9); GLD(10, 10); GLD(11, 11);
#pragma unroll
  for (int p = 0; p < 8; ++p)
    scLDS[p * 256 + tid] = scal4[b * T_STEPS + p * 256 + tid];
#pragma unroll
  for (int p = 0; p < 8; ++p)
    d45LDS[p * 256 + tid] = d45g[b * T_STEPS + p * 256 + tid];
  float4 h0v = ((const float4*)h0)[idx4];
  asm volatile("s_waitcnt vmcnt(0)" ::: "memory");

  // own-quarter W reads (each wave reads exactly what it staged: no barrier)
  float4 w0v = ldsW[0 * 256 + tid];
  float4 w1v = ldsW[1 * 256 + tid];
  float4 t2 = ldsW[2 * 256 + tid];
  float4 t3 = ldsW[3 * 256 + tid];
  float4 t4 = ldsW[4 * 256 + tid];
  float4 t5 = ldsW[5 * 256 + tid];

  h4[idx4] = h0v;  // slot 0 = h_0
  float4 s;
  s.x = h0v.x + w0v.x; s.y = h0v.y + w0v.y;
  s.z = h0v.z + w0v.z; s.w = h0v.w + w0v.w;

  // startup cross-wave dots
  {
    float q  = dpp_sum_reg(dot4(s, s));
    float r  = dpp_sum_reg(dot4(s, w1v));
    float c2 = dpp_sum_reg(dot4(s, t2));
    float c3 = dpp_sum_reg(dot4(s, t3));
    float c4 = dpp_sum_reg(dot4(s, t4));
    float c5 = dpp_sum_reg(dot4(s, t5));
    if (lane == 63) {
      initP[wave][0] = q;  initP[wave][1] = r;  initP[wave][2] = c2;
      initP[wave][3] = c3; initP[wave][4] = c4; initP[wave][5] = c5;
    }
  }
  __syncthreads();
  const float n1 = (initP[0][0] + initP[1][0]) + (initP[2][0] + initP[3][0]);
  float t1s = (initP[0][1] + initP[1][1]) + (initP[2][1] + initP[3][1]);
  float t2s = (initP[0][2] + initP[1][2]) + (initP[2][2] + initP[3][2]);
  float t3s = (initP[0][3] + initP[1][3]) + (initP[2][3] + initP[3][3]);
  float t4s = (initP[0][4] + initP[1][4]) + (initP[2][4] + initP[3][4]);
  float t5s = (initP[0][5] + initP[1][5]) + (initP[2][5] + initP[3][5]);
  const float B1 = t1s + t1s, C2 = t2s + t2s, C3 = t3s + t3s,
              C4 = t4s + t4s, C5 = t5s + t5s;
  // scal startup values (cross-wave entries -> only valid after the barrier)
  const float e1 = scLDS[1].x;
  float4 sc2v = scLDS[2], sc3v = scLDS[3], sc4v = scLDS[4], sc5v = scLDS[5];
  const float D45x = d45LDS[5].x;
  float4 scA = scLDS[6], scB = scLDS[7];
  float2 d45A = d45LDS[6], d45B = d45LDS[7];
  GLD(0, 12);  // slot 0 freed (w0v consumed) -> W_12

  float n = n1, rm1, rm2, rm3, rm4, pp;
  float gr0 = 0.f, gr1 = 0.f;
  float4 rv = make_float4(0.f, 0.f, 0.f, 0.f);
  float4 hvE, hvO, wSa, wSb, wGa, wGb;

#define BAR0 { asm volatile("s_waitcnt lgkmcnt(0)" ::: "memory"); __builtin_amdgcn_s_barrier(); }

  // ---- peel steps 1..5
  {  // step 1
    const float rinv = fast_rsq(fmaf(n, INVD, EPSV));
    n = fmaf(rinv, fmaf(rinv, n, B1), e1);
    hvO.x = rinv * s.x; hvO.y = rinv * s.y; hvO.z = rinv * s.z; hvO.w = rinv * s.w;
    h4[(size_t)SLOT4C * 1 + idx4] = hvO;
    s.x = hvO.x + w1v.x; s.y = hvO.y + w1v.y; s.z = hvO.z + w1v.z; s.w = hvO.w + w1v.w;
    float4 wg = ldsW[6 * 256 + tid];           // W_6
    pp = dpp_sum_reg(dot4(hvO, wg));           // G_6 partial
    GLD(1, 13);
    rm1 = rinv;
    BAR0
  }
  {  // step 2
    if (lane == 63) Gp[2][wave] = pp;          // target 6
    const float rinv = fast_rsq(fmaf(n, INVD, EPSV));
    const float BB = fmaf(rm1, C2, sc2v.y);
    n = fmaf(rinv, fmaf(rinv, n, BB), sc2v.x);
    hvE.x = rinv * s.x; hvE.y = rinv * s.y; hvE.z = rinv * s.z; hvE.w = rinv * s.w;
    h4[(size_t)SLOT4C * 2 + idx4] = hvE;
    s.x = hvE.x + t2.x; s.y = hvE.y + t2.y; s.z = hvE.z + t2.z; s.w = hvE.w + t2.w;
    float4 wg = ldsW[7 * 256 + tid];           // W_7
    pp = dpp_sum_reg(dot4(hvE, wg));           // G_7 partial
    GLD(2, 14);
    rm2 = rm1; rm1 = rinv;
    BAR0
  }
  {  // step 3
    if (lane == 63) Gp[3][wave] = pp;          // target 7
    const float rinv = fast_rsq(fmaf(n, INVD, EPSV));
    const float BB = fmaf(rm1, fmaf(rm2, C3, sc3v.z), sc3v.y);
    n = fmaf(rinv, fmaf(rinv, n, BB), sc3v.x);
    hvO.x = rinv * s.x; hvO.y = rinv * s.y; hvO.z = rinv * s.z; hvO.w = rinv * s.w;
    h4[(size_t)SLOT4C * 3 + idx4] = hvO;
    s.x = hvO.x + t3.x; s.y = hvO.y + t3.y; s.z = hvO.z + t3.z; s.w = hvO.w + t3.w;
    float4 wg = ldsW[8 * 256 + tid];           // W_8
    pp = dpp_sum_reg(dot4(hvO, wg));           // G_8 partial
    GLD(3, 15);
    rm3 = rm2; rm2 = rm1; rm1 = rinv;
    BAR0
  }
  {  // step 4
    if (lane == 63) Gp[0][wave] = pp;          // target 8
    const float rinv = fast_rsq(fmaf(n, INVD, EPSV));
    const float BB = fmaf(rm1, fmaf(rm2, fmaf(rm3, C4, sc4v.w), sc4v.z), sc4v.y);
    n = fmaf(rinv, fmaf(rinv, n, BB), sc4v.x);
    rv = *(const float4*)&Gp[2][0];            // target-6 partials
    hvE.x = rinv * s.x; hvE.y = rinv * s.y; hvE.z = rinv * s.z; hvE.w = rinv * s.w;
    h4[(size_t)SLOT4C * 4 + idx4] = hvE;
    s.x = hvE.x + t4.x; s.y = hvE.y + t4.y; s.z = hvE.z + t4.z; s.w = hvE.w + t4.w;
    float4 wg = ldsW[9 * 256 + tid];           // W_9
    pp = dpp_sum_reg(dot4(hvE, wg));           // G_9 partial
    GLD(4, 16);
    rm4 = rm3; rm3 = rm2; rm2 = rm1; rm1 = rinv;
    BAR0
  }
  {  // step 5
    if (lane == 63) Gp[1][wave] = pp;          // target 9
    const float rinv = fast_rsq(fmaf(n, INVD, EPSV));
    const float BB =
        fmaf(rm1, fmaf(rm2, fmaf(rm3, fmaf(rm4, C5, D45x), sc5v.w), sc5v.z), sc5v.y);
    n = fmaf(rinv, fmaf(rinv, n, BB), sc5v.x);
    { float gt = (rv.x + rv.y) + (rv.z + rv.w); gr0 = gt + gt; }  // 2*G_6
    rv = *(const float4*)&Gp[3][0];            // target-7 partials
    hvO.x = rinv * s.x; hvO.y = rinv * s.y; hvO.z = rinv * s.z; hvO.w = rinv * s.w;
    h4[(size_t)SLOT4C * 5 + idx4] = hvO;
    s.x = hvO.x + t5.x; s.y = hvO.y + t5.y; s.z = hvO.z + t5.z; s.w = hvO.w + t5.w;
    float4 wg = ldsW[10 * 256 + tid];          // W_10
    pp = dpp_sum_reg(dot4(hvO, wg));           // G_10 partial
    GLD(5, 17);
    wSa = ldsW[6 * 256 + tid];                 // W_6  (step-6 s-update)
    wGa = ldsW[11 * 256 + tid];                // W_11 (step-6 G-operand)
    rm4 = rm3; rm3 = rm2; rm2 = rm1; rm1 = rinv;
    BAR0
  }

// Steady step i>=6. VM/step: h-store + GLD (=2). DS/step: Gpw, rv, WP, WGP,
// sc, d45 (=6). vmcnt(10) at top (see kernel header); lgkmcnt(5) at barriers.
#define STEP(I_, SLW, SLG, SLP, GW, GR, SC, D45, GRU, GRW, WU, WGU, WP, WGP, HV, BAR_) \
  {                                                                                  \
    const int i_ = (I_);                                                             \
    asm volatile("s_waitcnt vmcnt(10)" ::: "memory");                                \
    if (lane == 63) Gp[GW][wave] = pp;                                               \
    { float gt_ = (rv.x + rv.y) + (rv.z + rv.w); GRW = gt_ + gt_; }                  \
    rv = *(const float4*)&Gp[GR][0];                                                 \
    WP = ldsW[(SLW) * 256 + tid];                                                    \
    WGP = ldsW[(SLG) * 256 + tid];                                                   \
    const float rinv = fast_rsq(fmaf(n, INVD, EPSV));                                \
    const float BB = fmaf(                                                           \
        rm1, fmaf(rm2, fmaf(rm3, fmaf(rm4, (D45).y + (GRU), (D45).x), (SC).w),       \
                  (SC).z), (SC).y);                                                  \
    n = fmaf(rinv, fmaf(rinv, n, BB), (SC).x);                                       \
    HV.x = rinv * s.x; HV.y = rinv * s.y; HV.z = rinv * s.z; HV.w = rinv * s.w;      \
    h4[(size_t)SLOT4C * i_ + idx4] = HV;                                             \
    s.x = HV.x + WU.x; s.y = HV.y + WU.y; s.z = HV.z + WU.z; s.w = HV.w + WU.w;      \
    pp = dpp_sum_reg(dot4(HV, WGU));                                                 \
    { const int wsrc_ = (i_ + 12 <= 2047) ? (i_ + 12) : 2047; GLD(SLP, wsrc_); }     \
    { const int isc_ = (i_ + 2 <= 2047) ? (i_ + 2) : 2047;                           \
      SC = scLDS[isc_]; D45 = d45LDS[isc_]; }                                        \
    rm4 = rm3; rm3 = rm2; rm2 = rm1; rm1 = rinv;                                     \
    if (BAR_) { asm volatile("s_waitcnt lgkmcnt(5)" ::: "memory");                   \
                __builtin_amdgcn_s_barrier(); }                                      \
  }

  // main loop: i = 6..2045 in chunks of 12 (ii ≡ 6 mod 12)
  for (int ii = 6; ii <= 2034; ii += 12) {
    STEP(ii + 0,  7,  0,  6, 2, 0, scA, d45A, gr0, gr1, wSa, wGa, wSb, wGb, hvE, 0)
    STEP(ii + 1,  8,  1,  7, 3, 1, scB, d45B, gr1, gr0, wSb, wGb, wSa, wGa, hvO, 1)
    STEP(ii + 2,  9,  2,  8, 0, 2, scA, d45A, gr0, gr1, wSa, wGa, wSb, wGb, hvE, 0)
    STEP(ii + 3, 10,  3,  9, 1, 3, scB, d45B, gr1, gr0, wSb, wGb, wSa, wGa, hvO, 1)
    STEP(ii + 4, 11,  4, 10, 2, 0, scA, d45A, gr0, gr1, wSa, wGa, wSb, wGb, hvE, 0)
    STEP(ii + 5,  0,  5, 11, 3, 1, scB, d45B, gr1, gr0, wSb, wGb, wSa, wGa, hvO, 1)
    STEP(ii + 6,  1,  6,  0, 0, 2, scA, d45A, gr0, gr1, wSa, wGa, wSb, wGb, hvE, 0)
    STEP(ii + 7,  2,  7,  1, 1, 3, scB, d45B, gr1, gr0, wSb, wGb, wSa, wGa, hvO, 1)
    STEP(ii + 8,  3,  8,  2, 2, 0, scA, d45A, gr0, gr1, wSa, wGa, wSb, wGb, hvE, 0)
    STEP(ii + 9,  4,  9,  3, 3, 1, scB, d45B, gr1, gr0, wSb, wGb, wSa, wGa, hvO, 1)
    STEP(ii + 10, 5, 10,  4, 0, 2, scA, d45A, gr0, gr1, wSa, wGa, wSb, wGb, hvE, 0)
    STEP(ii + 11, 6, 11,  5, 1, 3, scB, d45B, gr1, gr0, wSb, wGb, wSa, wGa, hvO, 1)
  }
  // tail: i = 2046 (≡6 mod 12), 2047 (≡7)
  STEP(2046, 7, 0, 6, 2, 0, scA, d45A, gr0, gr1, wSa, wGa, wSb, wGb, hvE, 0)
  STEP(2047, 8, 1, 7, 3, 1, scB, d45B, gr1, gr0, wSb, wGb, wSa, wGa, hvO, 1)
#undef STEP
#undef BAR0
#undef GLD

  // final: h_2048 = rinv * s -> slot 2048
  const float rinvT = fast_rsq(fmaf(n, INVD, EPSV));
  float4 o;
  o.x = rinvT * s.x; o.y = rinvT * s.y; o.z = rinvT * s.z; o.w = rinvT * s.w;
  h4[(size_t)SLOT4C * T_STEPS + idx4] = o;
}

// ---------------- outs[t] = h_{t+1} * silu(h_{t+1}) ----------------
__global__ __launch_bounds__(256) void silu_kernel(const float4* __restrict__ hsrc,
                                                   float4* __restrict__ out4, int n4) {
  int i = blockIdx.x * blockDim.x + threadIdx.x;
  if (i >= n4) return;
  float4 h = hsrc[i];
  float4 o;
  o.x = h.x * h.x / (1.f + __expf(-h.x));
  o.y = h.y * h.y / (1.f + __expf(-h.y));
  o.z = h.z * h.z / (1.f + __expf(-h.z));
  o.w = h.w * h.w / (1.f + __expf(-h.w));
  out4[i] = o;
}

extern "C" void kernel_launch(void* const* d_in, const int* in_sizes, int n_in,
                              void* d_out, int out_size, void* d_ws, size_t ws_size,
                              hipStream_t stream) {
  (void)in_sizes; (void)n_in; (void)d_ws; (void)ws_size; (void)out_size;
  const float* x = (const float*)d_in[0];
  const float* h0 = (const float*)d_in[1];
  const float* W = (const float*)d_in[2];
  const float* bias = (const float*)d_in[3];
  const float* log_alpha = (const float*)d_in[4];

  float* out = (float*)d_out;                               // outs region [T][B][D]
  float* hreg = out + (size_t)T_STEPS * BATCH * DIM;        // h region [T+1][B][D]
  // staging overlays the outs region (consumed before scan/silu touch it)
  __hip_bfloat16* xb = (__hip_bfloat16*)d_out;
  __hip_bfloat16* wb = (__hip_bfloat16*)((char*)d_out + (size_t)T_STEPS * BATCH * DIM * 2);
  float4* scal4 = (float4*)(out + (size_t)26 * 1024 * 1024);  // 104 MB offset
  float2* d45g = (float2*)(out + (size_t)27 * 1024 * 1024);   // 108 MB offset

  const int nx8 = T_STEPS * BATCH * DIM / 8;
  const int nw8 = DIM * DIM / 8;
  cvt_kernel<<<nx8 / 256, 256, 0, stream>>>(x, (bf16x8pack*)xb, nx8);
  cvt_kernel<<<nw8 / 256, 256, 0, stream>>>(W, (bf16x8pack*)wb, nw8);

  dim3 ggrid(DIM / 128, (T_STEPS * BATCH) / 128);
  gemm_kernel<<<ggrid, 256, 0, stream>>>(xb, wb, bias, log_alpha, hreg);

  dots_kernel<<<T_STEPS * BATCH, 64, 0, stream>>>(hreg, scal4, d45g);

  scan_kernel<<<BATCH, 256, 0, stream>>>(h0, scal4, d45g, hreg);

  const int n4 = T_STEPS * BATCH * DIM / 4;
  silu_kernel<<<n4 / 256, 256, 0, stream>>>((const float4*)(hreg + BATCH * DIM),
                                            (float4*)out, n4);
}

// Round 13
// 619.173 us; speedup vs baseline: 1.1406x; 1.1169x over previous
//
#include <hip/hip_runtime.h>
#include <hip/hip_bf16.h>

#define T_STEPS 2048
#define BATCH 16
#define DIM 1024
#define EPSV 1e-6f
#define INVD (1.0f / 1024.0f)
#define SLOTF (BATCH * DIM)      // floats per [B][D] slot
#define SLOT4C (BATCH * DIM / 4) // float4 per slot

typedef short short8 __attribute__((ext_vector_type(8)));
typedef float f32x4 __attribute__((ext_vector_type(4)));

struct alignas(16) bf16x8pack { __hip_bfloat16 v[8]; };

__device__ __forceinline__ float dot4(const float4& a, const float4& c) {
  return fmaf(a.x, c.x, fmaf(a.y, c.y, fmaf(a.z, c.z, a.w * c.w)));
}
__device__ __forceinline__ float fast_rsq(float x) {
  float r;
  asm("v_rsq_f32 %0, %1" : "=v"(r) : "v"(x));
  return r;
}

// ---------------- fp32 -> bf16 convert (vectorized) ----------------
__global__ __launch_bounds__(256) void cvt_kernel(const float* __restrict__ src,
                                                  bf16x8pack* __restrict__ dst, int n8) {
  int i = blockIdx.x * blockDim.x + threadIdx.x;
  if (i >= n8) return;
  const float4* s4 = (const float4*)src + (size_t)i * 2;
  float4 a = s4[0];
  float4 b = s4[1];
  bf16x8pack p;
  p.v[0] = __float2bfloat16(a.x); p.v[1] = __float2bfloat16(a.y);
  p.v[2] = __float2bfloat16(a.z); p.v[3] = __float2bfloat16(a.w);
  p.v[4] = __float2bfloat16(b.x); p.v[5] = __float2bfloat16(b.y);
  p.v[6] = __float2bfloat16(b.z); p.v[7] = __float2bfloat16(b.w);
  dst[i] = p;
}

// ---------------- bf16 MFMA GEMM: out[m][e] = alpha*(sum_d X[m][d]*W[e][d] + b[e]) ----
__global__ __launch_bounds__(256) void gemm_kernel(
    const __hip_bfloat16* __restrict__ Xb,
    const __hip_bfloat16* __restrict__ Wb,
    const float* __restrict__ bias,
    const float* __restrict__ log_alpha_p,
    float* __restrict__ hreg) {
  __shared__ __hip_bfloat16 As[128 * 32];
  __shared__ __hip_bfloat16 Bs[128 * 32];
  const int tid = threadIdx.x;
  const int wave = tid >> 6, lane = tid & 63;
  const int m0 = blockIdx.y * 128;
  const int e0 = blockIdx.x * 128;
  const int wm = (wave >> 1) * 64;
  const int wn = (wave & 1) * 64;
  const int l15 = lane & 15, l4 = lane >> 4;

  f32x4 acc[4][4] = {};

  const int srow = wave * 16 + (lane >> 2);
  const int sch = (lane & 3) * 8;

  for (int kt = 0; kt < DIM; kt += 32) {
    __syncthreads();
#pragma unroll
    for (int i = 0; i < 2; ++i) {
      const __hip_bfloat16* ga = Xb + (size_t)(m0 + i * 64 + srow) * DIM + kt + sch;
      const __hip_bfloat16* gb = Wb + (size_t)(e0 + i * 64 + srow) * DIM + kt + sch;
      __builtin_amdgcn_global_load_lds(
          (const __attribute__((address_space(1))) void*)ga,
          (__attribute__((address_space(3))) void*)((char*)As + (i * 64 + wave * 16) * 64),
          16, 0, 0);
      __builtin_amdgcn_global_load_lds(
          (const __attribute__((address_space(1))) void*)gb,
          (__attribute__((address_space(3))) void*)((char*)Bs + (i * 64 + wave * 16) * 64),
          16, 0, 0);
    }
    __syncthreads();
    short8 a[4], b[4];
#pragma unroll
    for (int f = 0; f < 4; ++f)
      a[f] = *(const short8*)((const char*)As + ((wm + f * 16 + l15) * 32 + l4 * 8) * 2);
#pragma unroll
    for (int g = 0; g < 4; ++g)
      b[g] = *(const short8*)((const char*)Bs + ((wn + g * 16 + l15) * 32 + l4 * 8) * 2);
#pragma unroll
    for (int f = 0; f < 4; ++f)
#pragma unroll
      for (int g = 0; g < 4; ++g)
        acc[f][g] = __builtin_amdgcn_mfma_f32_16x16x32_bf16(a[f], b[g], acc[f][g], 0, 0, 0);
  }
  const float alpha = __expf(log_alpha_p[0]);
#pragma unroll
  for (int g = 0; g < 4; ++g) {
    const int e = e0 + wn + g * 16 + l15;
    const float bv = bias[e];
#pragma unroll
    for (int f = 0; f < 4; ++f) {
#pragma unroll
      for (int r = 0; r < 4; ++r) {
        const int m = m0 + wm + f * 16 + l4 * 4 + r;
        hreg[(size_t)(m + BATCH) * DIM + e] = alpha * (acc[f][g][r] + bv);
      }
    }
  }
}

// ---------------- DPP wave-sum helper (total lands in lane 63) ----------------
__device__ __forceinline__ float dpp_sum_reg(float x) {
  float acc = x;
#define DPP_ADD(ctrl)                                                              \
  {                                                                                \
    int t_ = __builtin_amdgcn_update_dpp(0, __float_as_int(acc), (ctrl), 0xf, 0xf, \
                                         true);                                    \
    acc += __int_as_float(t_);                                                     \
  }
  DPP_ADD(0x111); DPP_ADD(0x112); DPP_ADD(0x114); DPP_ADD(0x118);
  DPP_ADD(0x142); DPP_ADD(0x143);
#undef DPP_ADD
  return acc;
}

// ---- precompute: scal4[t]=(e, 2d, 2d2, 2d3), d45[t]=(2d4, 2d5)  (dk = W_{t-k}.W_t) ----
__global__ __launch_bounds__(64) void dots_kernel(const float* __restrict__ hreg,
                                                  float4* __restrict__ scal4,
                                                  float2* __restrict__ d45g) {
  const int t = blockIdx.x >> 4;
  const int b = blockIdx.x & 15;
  const int lane = threadIdx.x;
  const float4* w  = (const float4*)(hreg + (size_t)(t + 1) * SLOTF + b * DIM);
  const float4* m1 = (const float4*)(hreg + (size_t)(t    ) * SLOTF + b * DIM);
  const float4* m2 = (const float4*)(hreg + (size_t)(t - 1) * SLOTF + b * DIM);
  const float4* m3 = (const float4*)(hreg + (size_t)(t - 2) * SLOTF + b * DIM);
  const float4* m4 = (const float4*)(hreg + (size_t)(t - 3) * SLOTF + b * DIM);
  const float4* m5 = (const float4*)(hreg + (size_t)(t - 4) * SLOTF + b * DIM);
  float e = 0.f, d = 0.f, d2 = 0.f, d3 = 0.f, d4 = 0.f, d5 = 0.f;
#pragma unroll
  for (int j = 0; j < 4; ++j) {
    float4 a = w[lane + 64 * j];
    e = fmaf(a.x, a.x, fmaf(a.y, a.y, fmaf(a.z, a.z, fmaf(a.w, a.w, e))));
    if (t >= 1) { float4 p = m1[lane + 64 * j];
      d = fmaf(p.x, a.x, fmaf(p.y, a.y, fmaf(p.z, a.z, fmaf(p.w, a.w, d)))); }
    if (t >= 2) { float4 p = m2[lane + 64 * j];
      d2 = fmaf(p.x, a.x, fmaf(p.y, a.y, fmaf(p.z, a.z, fmaf(p.w, a.w, d2)))); }
    if (t >= 3) { float4 p = m3[lane + 64 * j];
      d3 = fmaf(p.x, a.x, fmaf(p.y, a.y, fmaf(p.z, a.z, fmaf(p.w, a.w, d3)))); }
    if (t >= 4) { float4 p = m4[lane + 64 * j];
      d4 = fmaf(p.x, a.x, fmaf(p.y, a.y, fmaf(p.z, a.z, fmaf(p.w, a.w, d4)))); }
    if (t >= 5) { float4 p = m5[lane + 64 * j];
      d5 = fmaf(p.x, a.x, fmaf(p.y, a.y, fmaf(p.z, a.z, fmaf(p.w, a.w, d5)))); }
  }
  e = dpp_sum_reg(e);
  d = dpp_sum_reg(d);
  d2 = dpp_sum_reg(d2);
  d3 = dpp_sum_reg(d3);
  d4 = dpp_sum_reg(d4);
  d5 = dpp_sum_reg(d5);
  if (lane == 63) {
    scal4[b * T_STEPS + t] = make_float4(e, d + d, d2 + d2, d3 + d3);
    d45g[b * T_STEPS + t] = make_float2(d4 + d4, d5 + d5);
  }
}

// ---------------- scan: r7 (323us) structure + 2 ROWS PER BLOCK (TLP) ------------
// Mechanical transform of the proven r7 kernel: 512 threads = 8 waves = 2 batch
// rows x 4 waves. Each SIMD hosts 2 waves (one per row) -> the CU scheduler
// interleaves them, hiding the ~246 cy/step stall of one wave under the other's
// issue. All per-row state (scLDS/d45LDS/Gp/initP) duplicated; barriers are
// block-wide (both rows share cadence); step schedule/vmcnt/lgkm IDENTICAL.
__global__ __launch_bounds__(512, 1) void scan_kernel(
    const float* __restrict__ h0,
    const float4* __restrict__ scal4,
    const float2* __restrict__ d45g,
    float* __restrict__ hreg) {
  const int tid = threadIdx.x;
  const int wave = tid >> 6;
  const int row = wave >> 2;       // 0 or 1
  const int wv = wave & 3;         // wave within row
  const int lane = tid & 63;
  const int rtid = tid & 255;      // thread within row
  const int b = blockIdx.x * 2 + row;
  float4* h4 = (float4*)hreg;
  const int idx4 = b * 256 + rtid;

  __shared__ float4 scLDS[2][T_STEPS];          // 64 KB
  __shared__ float2 d45LDS[2][T_STEPS];         // 32 KB
  __shared__ alignas(16) float Gp[2][4][4];     // [row][target&3][wave-in-row]
  __shared__ float initP[2][4][6];

#pragma unroll
  for (int p = 0; p < 8; ++p)
    scLDS[row][p * 256 + rtid] = scal4[b * T_STEPS + p * 256 + rtid];
#pragma unroll
  for (int p = 0; p < 8; ++p)
    d45LDS[row][p * 256 + rtid] = d45g[b * T_STEPS + p * 256 + rtid];

  // W ring-16: w[k] = W_k for k=2..15, w[0]=W_16, w[1]=W_17  (W_j at hreg slot j+1)
  float4 w[16];
#pragma unroll
  for (int k = 2; k < 16; ++k) w[k] = h4[(size_t)SLOT4C * (k + 1) + idx4];
  w[0] = h4[(size_t)SLOT4C * 17 + idx4];
  w[1] = h4[(size_t)SLOT4C * 18 + idx4];
  float4 w0v = h4[(size_t)SLOT4C * 1 + idx4];  // W_0
  float4 w1v = h4[(size_t)SLOT4C * 2 + idx4];  // W_1
  float4 h0v = ((const float4*)h0)[idx4];
  h4[idx4] = h0v;  // slot 0 = h_0

  // startup direct reductions off s_1 = h_0 + W_0
  float4 s;
  s.x = h0v.x + w0v.x; s.y = h0v.y + w0v.y;
  s.z = h0v.z + w0v.z; s.w = h0v.w + w0v.w;
  {
    float q  = dpp_sum_reg(dot4(s, s));
    float r  = dpp_sum_reg(dot4(s, w1v));
    float c2 = dpp_sum_reg(dot4(s, w[2]));
    float c3 = dpp_sum_reg(dot4(s, w[3]));
    float c4 = dpp_sum_reg(dot4(s, w[4]));
    float c5 = dpp_sum_reg(dot4(s, w[5]));
    if (lane == 63) {
      initP[row][wv][0] = q;  initP[row][wv][1] = r;  initP[row][wv][2] = c2;
      initP[row][wv][3] = c3; initP[row][wv][4] = c4; initP[row][wv][5] = c5;
    }
  }
  __syncthreads();
  const float n1 = (initP[row][0][0] + initP[row][1][0]) +
                   (initP[row][2][0] + initP[row][3][0]);
  float t1 = (initP[row][0][1] + initP[row][1][1]) + (initP[row][2][1] + initP[row][3][1]);
  float t2 = (initP[row][0][2] + initP[row][1][2]) + (initP[row][2][2] + initP[row][3][2]);
  float t3 = (initP[row][0][3] + initP[row][1][3]) + (initP[row][2][3] + initP[row][3][3]);
  float t4 = (initP[row][0][4] + initP[row][1][4]) + (initP[row][2][4] + initP[row][3][4]);
  float t5 = (initP[row][0][5] + initP[row][1][5]) + (initP[row][2][5] + initP[row][3][5]);
  const float B1 = t1 + t1, C2 = t2 + t2, C3 = t3 + t3, C4 = t4 + t4, C5 = t5 + t5;

  const float e1 = scLDS[row][1].x;
  float4 sc2 = scLDS[row][2], sc3 = scLDS[row][3], sc4 = scLDS[row][4], sc5 = scLDS[row][5];
  const float D45x = d45LDS[row][5].x;  // 2*d4_5
  float4 scA = scLDS[row][6], scB = scLDS[row][7];
  float2 d45A = d45LDS[row][6], d45B = d45LDS[row][7];

  float n = n1, rm1, rm2, rm3, rm4, pp;
  float gr0 = 0.f, gr1 = 0.f;
  float4 rv = make_float4(0.f, 0.f, 0.f, 0.f);
  float4 hvr[4];  // store-data register ring (static indices)

#define BAR0 { asm volatile("s_waitcnt lgkmcnt(0)" ::: "memory"); __builtin_amdgcn_s_barrier(); }

  // ---- step 1
  {
    const float rinv = fast_rsq(fmaf(n, INVD, EPSV));
    n = fmaf(rinv, fmaf(rinv, n, B1), e1);
    hvr[1].x = rinv * s.x; hvr[1].y = rinv * s.y;
    hvr[1].z = rinv * s.z; hvr[1].w = rinv * s.w;
    h4[(size_t)SLOT4C * 1 + idx4] = hvr[1];
    s.x = hvr[1].x + w1v.x; s.y = hvr[1].y + w1v.y;
    s.z = hvr[1].z + w1v.z; s.w = hvr[1].w + w1v.w;
    pp = dpp_sum_reg(dot4(hvr[1], w[6]));  // G_6 partial
    rm1 = rinv;
    BAR0
  }
  // ---- step 2
  {
    if (lane == 63) Gp[row][2][wv] = pp;  // target 6
    const float rinv = fast_rsq(fmaf(n, INVD, EPSV));
    const float BB = fmaf(rm1, C2, sc2.y);
    n = fmaf(rinv, fmaf(rinv, n, BB), sc2.x);
    hvr[2].x = rinv * s.x; hvr[2].y = rinv * s.y;
    hvr[2].z = rinv * s.z; hvr[2].w = rinv * s.w;
    h4[(size_t)SLOT4C * 2 + idx4] = hvr[2];
    s.x = hvr[2].x + w[2].x; s.y = hvr[2].y + w[2].y;
    s.z = hvr[2].z + w[2].z; s.w = hvr[2].w + w[2].w;
    pp = dpp_sum_reg(dot4(hvr[2], w[7]));  // G_7 partial
    w[2] = h4[(size_t)SLOT4C * 19 + idx4];  // W_18
    rm2 = rm1; rm1 = rinv;
    BAR0
  }
  // ---- step 3
  {
    if (lane == 63) Gp[row][3][wv] = pp;  // target 7
    const float rinv = fast_rsq(fmaf(n, INVD, EPSV));
    const float BB = fmaf(rm1, fmaf(rm2, C3, sc3.z), sc3.y);
    n = fmaf(rinv, fmaf(rinv, n, BB), sc3.x);
    hvr[3].x = rinv * s.x; hvr[3].y = rinv * s.y;
    hvr[3].z = rinv * s.z; hvr[3].w = rinv * s.w;
    h4[(size_t)SLOT4C * 3 + idx4] = hvr[3];
    s.x = hvr[3].x + w[3].x; s.y = hvr[3].y + w[3].y;
    s.z = hvr[3].z + w[3].z; s.w = hvr[3].w + w[3].w;
    pp = dpp_sum_reg(dot4(hvr[3], w[8]));  // G_8 partial
    w[3] = h4[(size_t)SLOT4C * 20 + idx4];  // W_19
    rm3 = rm2; rm2 = rm1; rm1 = rinv;
    BAR0
  }
  // ---- step 4
  {
    if (lane == 63) Gp[row][0][wv] = pp;  // target 8
    const float rinv = fast_rsq(fmaf(n, INVD, EPSV));
    const float BB = fmaf(rm1, fmaf(rm2, fmaf(rm3, C4, sc4.w), sc4.z), sc4.y);
    n = fmaf(rinv, fmaf(rinv, n, BB), sc4.x);
    rv = *(const float4*)&Gp[row][2][0];  // target-6 partials
    hvr[0].x = rinv * s.x; hvr[0].y = rinv * s.y;
    hvr[0].z = rinv * s.z; hvr[0].w = rinv * s.w;
    h4[(size_t)SLOT4C * 4 + idx4] = hvr[0];
    s.x = hvr[0].x + w[4].x; s.y = hvr[0].y + w[4].y;
    s.z = hvr[0].z + w[4].z; s.w = hvr[0].w + w[4].w;
    pp = dpp_sum_reg(dot4(hvr[0], w[9]));  // G_9 partial
    w[4] = h4[(size_t)SLOT4C * 21 + idx4];  // W_20
    rm4 = rm3; rm3 = rm2; rm2 = rm1; rm1 = rinv;
    BAR0
  }
  // ---- step 5
  {
    if (lane == 63) Gp[row][1][wv] = pp;  // target 9
    const float rinv = fast_rsq(fmaf(n, INVD, EPSV));
    const float BB =
        fmaf(rm1, fmaf(rm2, fmaf(rm3, fmaf(rm4, C5, D45x), sc5.w), sc5.z), sc5.y);
    n = fmaf(rinv, fmaf(rinv, n, BB), sc5.x);
    { float gt = (rv.x + rv.y) + (rv.z + rv.w); gr0 = gt + gt; }  // 2*G_6
    rv = *(const float4*)&Gp[row][3][0];  // target-7 partials
    hvr[1].x = rinv * s.x; hvr[1].y = rinv * s.y;
    hvr[1].z = rinv * s.z; hvr[1].w = rinv * s.w;
    h4[(size_t)SLOT4C * 5 + idx4] = hvr[1];
    s.x = hvr[1].x + w[5].x; s.y = hvr[1].y + w[5].y;
    s.z = hvr[1].z + w[5].z; s.w = hvr[1].w + w[5].w;
    pp = dpp_sum_reg(dot4(hvr[1], w[10]));  // G_10 partial
    w[5] = h4[(size_t)SLOT4C * 22 + idx4];  // W_21
    rm4 = rm3; rm3 = rm2; rm2 = rm1; rm1 = rinv;
    BAR0
  }

// Steady step i>=6 (identical to r7, with per-row Gp/scLDS/d45LDS).
#define STEP(I_, WS, W5S, GW, GR, SCR, D45R, GRU, GRW, HVI, BAR_)                    \
  {                                                                                  \
    const int i_ = (I_);                                                             \
    if (lane == 63) Gp[row][GW][wv] = pp;                                            \
    { float gt_ = (rv.x + rv.y) + (rv.z + rv.w); GRW = gt_ + gt_; }                  \
    rv = *(const float4*)&Gp[row][GR][0];                                            \
    const float rinv = fast_rsq(fmaf(n, INVD, EPSV));                                \
    const float BB = fmaf(                                                           \
        rm1, fmaf(rm2, fmaf(rm3, fmaf(rm4, (D45R).y + (GRU), (D45R).x), (SCR).w),    \
                  (SCR).z), (SCR).y);                                                \
    n = fmaf(rinv, fmaf(rinv, n, BB), (SCR).x);                                      \
    hvr[HVI].x = rinv * s.x; hvr[HVI].y = rinv * s.y;                                \
    hvr[HVI].z = rinv * s.z; hvr[HVI].w = rinv * s.w;                                \
    h4[(size_t)SLOT4C * i_ + idx4] = hvr[HVI];                                       \
    s.x = hvr[HVI].x + w[WS].x; s.y = hvr[HVI].y + w[WS].y;                          \
    s.z = hvr[HVI].z + w[WS].z; s.w = hvr[HVI].w + w[WS].w;                          \
    pp = dpp_sum_reg(dot4(hvr[HVI], w[W5S]));                                        \
    const int ipf_ = (i_ + 16 < T_STEPS) ? (i_ + 16) : (T_STEPS - 1);                \
    w[WS] = h4[(size_t)SLOT4C * (ipf_ + 1) + idx4];                                  \
    const int isc_ = (i_ + 2 < T_STEPS) ? (i_ + 2) : (T_STEPS - 1);                  \
    SCR = scLDS[row][isc_];                                                          \
    D45R = d45LDS[row][isc_];                                                        \
    rm4 = rm3; rm3 = rm2; rm2 = rm1; rm1 = rinv;                                     \
    if (BAR_) { asm volatile("s_waitcnt lgkmcnt(3)" ::: "memory");                   \
                __builtin_amdgcn_s_barrier(); }                                      \
  }

  // main loop: i = 6..2037 in chunks of 16 (ii ≡ 6 mod 16); HVI = i&3
  for (int ii = 6; ii < 2038; ii += 16) {
    STEP(ii + 0,  6, 11, 2, 0, scA, d45A, gr0, gr1, 2, 0)
    STEP(ii + 1,  7, 12, 3, 1, scB, d45B, gr1, gr0, 3, 1)
    STEP(ii + 2,  8, 13, 0, 2, scA, d45A, gr0, gr1, 0, 0)
    STEP(ii + 3,  9, 14, 1, 3, scB, d45B, gr1, gr0, 1, 1)
    STEP(ii + 4, 10, 15, 2, 0, scA, d45A, gr0, gr1, 2, 0)
    STEP(ii + 5, 11,  0, 3, 1, scB, d45B, gr1, gr0, 3, 1)
    STEP(ii + 6, 12,  1, 0, 2, scA, d45A, gr0, gr1, 0, 0)
    STEP(ii + 7, 13,  2, 1, 3, scB, d45B, gr1, gr0, 1, 1)
    STEP(ii + 8, 14,  3, 2, 0, scA, d45A, gr0, gr1, 2, 0)
    STEP(ii + 9, 15,  4, 3, 1, scB, d45B, gr1, gr0, 3, 1)
    STEP(ii + 10, 0,  5, 0, 2, scA, d45A, gr0, gr1, 0, 0)
    STEP(ii + 11, 1,  6, 1, 3, scB, d45B, gr1, gr0, 1, 1)
    STEP(ii + 12, 2,  7, 2, 0, scA, d45A, gr0, gr1, 2, 0)
    STEP(ii + 13, 3,  8, 3, 1, scB, d45B, gr1, gr0, 3, 1)
    STEP(ii + 14, 4,  9, 0, 2, scA, d45A, gr0, gr1, 0, 0)
    STEP(ii + 15, 5, 10, 1, 3, scB, d45B, gr1, gr0, 1, 1)
  }
  // tail: i = 2038..2047 (continues pattern, 2038 ≡ 6 mod 16)
  STEP(2038,  6, 11, 2, 0, scA, d45A, gr0, gr1, 2, 0)
  STEP(2039,  7, 12, 3, 1, scB, d45B, gr1, gr0, 3, 1)
  STEP(2040,  8, 13, 0, 2, scA, d45A, gr0, gr1, 0, 0)
  STEP(2041,  9, 14, 1, 3, scB, d45B, gr1, gr0, 1, 1)
  STEP(2042, 10, 15, 2, 0, scA, d45A, gr0, gr1, 2, 0)
  STEP(2043, 11,  0, 3, 1, scB, d45B, gr1, gr0, 3, 1)
  STEP(2044, 12,  1, 0, 2, scA, d45A, gr0, gr1, 0, 0)
  STEP(2045, 13,  2, 1, 3, scB, d45B, gr1, gr0, 1, 1)
  STEP(2046, 14,  3, 2, 0, scA, d45A, gr0, gr1, 2, 0)
  STEP(2047, 15,  4, 3, 1, scB, d45B, gr1, gr0, 3, 1)
#undef STEP
#undef BAR0

  // final: h_2048 = rinv * s -> slot 2048
  const float rinvT = fast_rsq(fmaf(n, INVD, EPSV));
  float4 o;
  o.x = rinvT * s.x; o.y = rinvT * s.y; o.z = rinvT * s.z; o.w = rinvT * s.w;
  h4[(size_t)SLOT4C * T_STEPS + idx4] = o;
}

// ---------------- outs[t] = h_{t+1} * silu(h_{t+1}) ----------------
__global__ __launch_bounds__(256) void silu_kernel(const float4* __restrict__ hsrc,
                                                   float4* __restrict__ out4, int n4) {
  int i = blockIdx.x * blockDim.x + threadIdx.x;
  if (i >= n4) return;
  float4 h = hsrc[i];
  float4 o;
  o.x = h.x * h.x / (1.f + __expf(-h.x));
  o.y = h.y * h.y / (1.f + __expf(-h.y));
  o.z = h.z * h.z / (1.f + __expf(-h.z));
  o.w = h.w * h.w / (1.f + __expf(-h.w));
  out4[i] = o;
}

extern "C" void kernel_launch(void* const* d_in, const int* in_sizes, int n_in,
                              void* d_out, int out_size, void* d_ws, size_t ws_size,
                              hipStream_t stream) {
  (void)in_sizes; (void)n_in; (void)d_ws; (void)ws_size; (void)out_size;
  const float* x = (const float*)d_in[0];
  const float* h0 = (const float*)d_in[1];
  const float* W = (const float*)d_in[2];
  const float* bias = (const float*)d_in[3];
  const float* log_alpha = (const float*)d_in[4];

  float* out = (float*)d_out;                               // outs region [T][B][D]
  float* hreg = out + (size_t)T_STEPS * BATCH * DIM;        // h region [T+1][B][D]
  // staging overlays the outs region (consumed before scan/silu touch it)
  __hip_bfloat16* xb = (__hip_bfloat16*)d_out;
  __hip_bfloat16* wb = (__hip_bfloat16*)((char*)d_out + (size_t)T_STEPS * BATCH * DIM * 2);
  float4* scal4 = (float4*)(out + (size_t)26 * 1024 * 1024);  // 104 MB offset
  float2* d45g = (float2*)(out + (size_t)27 * 1024 * 1024);   // 108 MB offset

  const int nx8 = T_STEPS * BATCH * DIM / 8;
  const int nw8 = DIM * DIM / 8;
  cvt_kernel<<<nx8 / 256, 256, 0, stream>>>(x, (bf16x8pack*)xb, nx8);
  cvt_kernel<<<nw8 / 256, 256, 0, stream>>>(W, (bf16x8pack*)wb, nw8);

  dim3 ggrid(DIM / 128, (T_STEPS * BATCH) / 128);
  gemm_kernel<<<ggrid, 256, 0, stream>>>(xb, wb, bias, log_alpha, hreg);

  dots_kernel<<<T_STEPS * BATCH, 64, 0, stream>>>(hreg, scal4, d45g);

  scan_kernel<<<BATCH / 2, 512, 0, stream>>>(h0, scal4, d45g, hreg);

  const int n4 = T_STEPS * BATCH * DIM / 4;
  silu_kernel<<<n4 / 256, 256, 0, stream>>>((const float4*)(hreg + BATCH * DIM),
                                            (float4*)out, n4);
}

// Round 14
// 599.085 us; speedup vs baseline: 1.1789x; 1.0335x over previous
//
#include <hip/hip_runtime.h>
#include <hip/hip_bf16.h>

#define T_STEPS 2048
#define BATCH 16
#define DIM 1024
#define EPSV 1e-6f
#define INVD (1.0f / 1024.0f)
#define SLOTF (BATCH * DIM)      // floats per [B][D] slot
#define SLOT4C (BATCH * DIM / 4) // float4 per slot

typedef short short8 __attribute__((ext_vector_type(8)));
typedef float f32x4 __attribute__((ext_vector_type(4)));

struct alignas(16) bf16x8pack { __hip_bfloat16 v[8]; };

__device__ __forceinline__ float dot4(const float4& a, const float4& c) {
  return fmaf(a.x, c.x, fmaf(a.y, c.y, fmaf(a.z, c.z, a.w * c.w)));
}
__device__ __forceinline__ float fast_rsq(float x) {
  float r;
  asm("v_rsq_f32 %0, %1" : "=v"(r) : "v"(x));
  return r;
}
__device__ __forceinline__ float fast_rcp(float x) {
  float r;
  asm("v_rcp_f32 %0, %1" : "=v"(r) : "v"(x));
  return r;
}
__device__ __forceinline__ float silu_prod(float h) {
  // h * silu(h) = h*h / (1 + exp(-h));  raw v_rcp (~1ulp) is fine vs 0.55 threshold
  return h * h * fast_rcp(1.0f + __expf(-h));
}

// ---------------- fp32 -> bf16 convert (vectorized) ----------------
__global__ __launch_bounds__(256) void cvt_kernel(const float* __restrict__ src,
                                                  bf16x8pack* __restrict__ dst, int n8) {
  int i = blockIdx.x * blockDim.x + threadIdx.x;
  if (i >= n8) return;
  const float4* s4 = (const float4*)src + (size_t)i * 2;
  float4 a = s4[0];
  float4 b = s4[1];
  bf16x8pack p;
  p.v[0] = __float2bfloat16(a.x); p.v[1] = __float2bfloat16(a.y);
  p.v[2] = __float2bfloat16(a.z); p.v[3] = __float2bfloat16(a.w);
  p.v[4] = __float2bfloat16(b.x); p.v[5] = __float2bfloat16(b.y);
  p.v[6] = __float2bfloat16(b.z); p.v[7] = __float2bfloat16(b.w);
  dst[i] = p;
}

// ---------------- bf16 MFMA GEMM: out[m][e] = alpha*(sum_d X[m][d]*W[e][d] + b[e]) ----
__global__ __launch_bounds__(256) void gemm_kernel(
    const __hip_bfloat16* __restrict__ Xb,
    const __hip_bfloat16* __restrict__ Wb,
    const float* __restrict__ bias,
    const float* __restrict__ log_alpha_p,
    float* __restrict__ hreg) {
  __shared__ __hip_bfloat16 As[128 * 32];
  __shared__ __hip_bfloat16 Bs[128 * 32];
  const int tid = threadIdx.x;
  const int wave = tid >> 6, lane = tid & 63;
  const int m0 = blockIdx.y * 128;
  const int e0 = blockIdx.x * 128;
  const int wm = (wave >> 1) * 64;
  const int wn = (wave & 1) * 64;
  const int l15 = lane & 15, l4 = lane >> 4;

  f32x4 acc[4][4] = {};

  const int srow = wave * 16 + (lane >> 2);
  const int sch = (lane & 3) * 8;

  for (int kt = 0; kt < DIM; kt += 32) {
    __syncthreads();
#pragma unroll
    for (int i = 0; i < 2; ++i) {
      const __hip_bfloat16* ga = Xb + (size_t)(m0 + i * 64 + srow) * DIM + kt + sch;
      const __hip_bfloat16* gb = Wb + (size_t)(e0 + i * 64 + srow) * DIM + kt + sch;
      __builtin_amdgcn_global_load_lds(
          (const __attribute__((address_space(1))) void*)ga,
          (__attribute__((address_space(3))) void*)((char*)As + (i * 64 + wave * 16) * 64),
          16, 0, 0);
      __builtin_amdgcn_global_load_lds(
          (const __attribute__((address_space(1))) void*)gb,
          (__attribute__((address_space(3))) void*)((char*)Bs + (i * 64 + wave * 16) * 64),
          16, 0, 0);
    }
    __syncthreads();
    short8 a[4], b[4];
#pragma unroll
    for (int f = 0; f < 4; ++f)
      a[f] = *(const short8*)((const char*)As + ((wm + f * 16 + l15) * 32 + l4 * 8) * 2);
#pragma unroll
    for (int g = 0; g < 4; ++g)
      b[g] = *(const short8*)((const char*)Bs + ((wn + g * 16 + l15) * 32 + l4 * 8) * 2);
#pragma unroll
    for (int f = 0; f < 4; ++f)
#pragma unroll
      for (int g = 0; g < 4; ++g)
        acc[f][g] = __builtin_amdgcn_mfma_f32_16x16x32_bf16(a[f], b[g], acc[f][g], 0, 0, 0);
  }
  const float alpha = __expf(log_alpha_p[0]);
#pragma unroll
  for (int g = 0; g < 4; ++g) {
    const int e = e0 + wn + g * 16 + l15;
    const float bv = bias[e];
#pragma unroll
    for (int f = 0; f < 4; ++f) {
#pragma unroll
      for (int r = 0; r < 4; ++r) {
        const int m = m0 + wm + f * 16 + l4 * 4 + r;
        hreg[(size_t)(m + BATCH) * DIM + e] = alpha * (acc[f][g][r] + bv);
      }
    }
  }
}

// ---------------- DPP wave-sum helper (total lands in lane 63) ----------------
__device__ __forceinline__ float dpp_sum_reg(float x) {
  float acc = x;
#define DPP_ADD(ctrl)                                                              \
  {                                                                                \
    int t_ = __builtin_amdgcn_update_dpp(0, __float_as_int(acc), (ctrl), 0xf, 0xf, \
                                         true);                                    \
    acc += __int_as_float(t_);                                                     \
  }
  DPP_ADD(0x111); DPP_ADD(0x112); DPP_ADD(0x114); DPP_ADD(0x118);
  DPP_ADD(0x142); DPP_ADD(0x143);
#undef DPP_ADD
  return acc;
}

// ---- precompute: scal4[t]=(e, 2d, 2d2, 2d3), d45[t]=(2d4, 2d5)  (dk = W_{t-k}.W_t) ----
__global__ __launch_bounds__(64) void dots_kernel(const float* __restrict__ hreg,
                                                  float4* __restrict__ scal4,
                                                  float2* __restrict__ d45g) {
  const int t = blockIdx.x >> 4;
  const int b = blockIdx.x & 15;
  const int lane = threadIdx.x;
  const float4* w  = (const float4*)(hreg + (size_t)(t + 1) * SLOTF + b * DIM);
  const float4* m1 = (const float4*)(hreg + (size_t)(t    ) * SLOTF + b * DIM);
  const float4* m2 = (const float4*)(hreg + (size_t)(t - 1) * SLOTF + b * DIM);
  const float4* m3 = (const float4*)(hreg + (size_t)(t - 2) * SLOTF + b * DIM);
  const float4* m4 = (const float4*)(hreg + (size_t)(t - 3) * SLOTF + b * DIM);
  const float4* m5 = (const float4*)(hreg + (size_t)(t - 4) * SLOTF + b * DIM);
  float e = 0.f, d = 0.f, d2 = 0.f, d3 = 0.f, d4 = 0.f, d5 = 0.f;
#pragma unroll
  for (int j = 0; j < 4; ++j) {
    float4 a = w[lane + 64 * j];
    e = fmaf(a.x, a.x, fmaf(a.y, a.y, fmaf(a.z, a.z, fmaf(a.w, a.w, e))));
    if (t >= 1) { float4 p = m1[lane + 64 * j];
      d = fmaf(p.x, a.x, fmaf(p.y, a.y, fmaf(p.z, a.z, fmaf(p.w, a.w, d)))); }
    if (t >= 2) { float4 p = m2[lane + 64 * j];
      d2 = fmaf(p.x, a.x, fmaf(p.y, a.y, fmaf(p.z, a.z, fmaf(p.w, a.w, d2)))); }
    if (t >= 3) { float4 p = m3[lane + 64 * j];
      d3 = fmaf(p.x, a.x, fmaf(p.y, a.y, fmaf(p.z, a.z, fmaf(p.w, a.w, d3)))); }
    if (t >= 4) { float4 p = m4[lane + 64 * j];
      d4 = fmaf(p.x, a.x, fmaf(p.y, a.y, fmaf(p.z, a.z, fmaf(p.w, a.w, d4)))); }
    if (t >= 5) { float4 p = m5[lane + 64 * j];
      d5 = fmaf(p.x, a.x, fmaf(p.y, a.y, fmaf(p.z, a.z, fmaf(p.w, a.w, d5)))); }
  }
  e = dpp_sum_reg(e);
  d = dpp_sum_reg(d);
  d2 = dpp_sum_reg(d2);
  d3 = dpp_sum_reg(d3);
  d4 = dpp_sum_reg(d4);
  d5 = dpp_sum_reg(d5);
  if (lane == 63) {
    scal4[b * T_STEPS + t] = make_float4(e, d + d, d2 + d2, d3 + d3);
    d45g[b * T_STEPS + t] = make_float2(d4 + d4, d5 + d5);
  }
}

// ---------------- scan (r7 structure, 323us) + FUSED SILU OUTPUT ------------------
// Single change vs the proven r7 kernel: each step also computes
// out[i-1] = h_i * silu(h_i) from the in-register hvr and stores it, deleting the
// separate silu pass (536 MB HBM round-trip). Scan HBM write rate doubles to
// ~1 TB/s (12% of peak: no BW risk); added issue ~24 VALU + 8 TRANS + 1 store
// per step, largely absorbed by the step's existing stall window.
// SAFETY: out-store at step i touches out slot i-1. Prior contents there are
// dead: xb/wb (GEMM input staging, consumed stream-ordered before scan) and
// scal4/d45g at out slots ~1586-1660, which every block LDS-stages in its
// prologue ~250us before ANY block can reach step 1586 (all 16 blocks dispatch
// in one CP wavefront; no cross-block data dependency on those regions after
// the prologue).
__global__ __launch_bounds__(256, 1) void scan_kernel(
    const float* __restrict__ h0,
    const float4* __restrict__ scal4,
    const float2* __restrict__ d45g,
    float* __restrict__ hreg,
    float* __restrict__ outp) {
  const int b = blockIdx.x;
  const int tid = threadIdx.x;
  const int wave = tid >> 6;
  const int lane = tid & 63;
  float4* h4 = (float4*)hreg;
  float4* o4 = (float4*)outp;
  const int idx4 = b * 256 + tid;

  __shared__ float4 scLDS[T_STEPS];          // 32 KB
  __shared__ float2 d45LDS[T_STEPS];         // 16 KB
  __shared__ alignas(16) float Gp[4][4];     // [target&3][wave]
  __shared__ float initP[4][6];

#pragma unroll
  for (int p = 0; p < 8; ++p)
    scLDS[p * 256 + tid] = scal4[b * T_STEPS + p * 256 + tid];
#pragma unroll
  for (int p = 0; p < 8; ++p)
    d45LDS[p * 256 + tid] = d45g[b * T_STEPS + p * 256 + tid];

  // W ring-16: w[k] = W_k for k=2..15, w[0]=W_16, w[1]=W_17  (W_j at hreg slot j+1)
  float4 w[16];
#pragma unroll
  for (int k = 2; k < 16; ++k) w[k] = h4[(size_t)SLOT4C * (k + 1) + idx4];
  w[0] = h4[(size_t)SLOT4C * 17 + idx4];
  w[1] = h4[(size_t)SLOT4C * 18 + idx4];
  float4 w0v = h4[(size_t)SLOT4C * 1 + idx4];  // W_0
  float4 w1v = h4[(size_t)SLOT4C * 2 + idx4];  // W_1
  float4 h0v = ((const float4*)h0)[idx4];
  h4[idx4] = h0v;  // slot 0 = h_0

  // startup direct reductions off s_1 = h_0 + W_0
  float4 s;
  s.x = h0v.x + w0v.x; s.y = h0v.y + w0v.y;
  s.z = h0v.z + w0v.z; s.w = h0v.w + w0v.w;
  {
    float q  = dpp_sum_reg(dot4(s, s));
    float r  = dpp_sum_reg(dot4(s, w1v));
    float c2 = dpp_sum_reg(dot4(s, w[2]));
    float c3 = dpp_sum_reg(dot4(s, w[3]));
    float c4 = dpp_sum_reg(dot4(s, w[4]));
    float c5 = dpp_sum_reg(dot4(s, w[5]));
    if (lane == 63) {
      initP[wave][0] = q;  initP[wave][1] = r;  initP[wave][2] = c2;
      initP[wave][3] = c3; initP[wave][4] = c4; initP[wave][5] = c5;
    }
  }
  __syncthreads();
  const float n1 = (initP[0][0] + initP[1][0]) + (initP[2][0] + initP[3][0]);
  float t1 = (initP[0][1] + initP[1][1]) + (initP[2][1] + initP[3][1]);
  float t2 = (initP[0][2] + initP[1][2]) + (initP[2][2] + initP[3][2]);
  float t3 = (initP[0][3] + initP[1][3]) + (initP[2][3] + initP[3][3]);
  float t4 = (initP[0][4] + initP[1][4]) + (initP[2][4] + initP[3][4]);
  float t5 = (initP[0][5] + initP[1][5]) + (initP[2][5] + initP[3][5]);
  const float B1 = t1 + t1, C2 = t2 + t2, C3 = t3 + t3, C4 = t4 + t4, C5 = t5 + t5;

  const float e1 = scLDS[1].x;
  float4 sc2 = scLDS[2], sc3 = scLDS[3], sc4 = scLDS[4], sc5 = scLDS[5];
  const float D45x = d45LDS[5].x;  // 2*d4_5
  float4 scA = scLDS[6], scB = scLDS[7];
  float2 d45A = d45LDS[6], d45B = d45LDS[7];

  float n = n1, rm1, rm2, rm3, rm4, pp;
  float gr0 = 0.f, gr1 = 0.f;
  float4 rv = make_float4(0.f, 0.f, 0.f, 0.f);
  float4 hvr[4];  // store-data register ring (static indices)

#define SILOUT(HV, I_)                                                             \
  {                                                                                \
    float4 o_;                                                                     \
    o_.x = silu_prod(HV.x); o_.y = silu_prod(HV.y);                                \
    o_.z = silu_prod(HV.z); o_.w = silu_prod(HV.w);                                \
    o4[(size_t)SLOT4C * ((I_) - 1) + idx4] = o_;                                   \
  }

#define BAR0 { asm volatile("s_waitcnt lgkmcnt(0)" ::: "memory"); __builtin_amdgcn_s_barrier(); }

  // ---- step 1
  {
    const float rinv = fast_rsq(fmaf(n, INVD, EPSV));
    n = fmaf(rinv, fmaf(rinv, n, B1), e1);
    hvr[1].x = rinv * s.x; hvr[1].y = rinv * s.y;
    hvr[1].z = rinv * s.z; hvr[1].w = rinv * s.w;
    h4[(size_t)SLOT4C * 1 + idx4] = hvr[1];
    s.x = hvr[1].x + w1v.x; s.y = hvr[1].y + w1v.y;
    s.z = hvr[1].z + w1v.z; s.w = hvr[1].w + w1v.w;
    pp = dpp_sum_reg(dot4(hvr[1], w[6]));  // G_6 partial
    SILOUT(hvr[1], 1)
    rm1 = rinv;
    BAR0
  }
  // ---- step 2
  {
    if (lane == 63) Gp[2][wave] = pp;  // target 6
    const float rinv = fast_rsq(fmaf(n, INVD, EPSV));
    const float BB = fmaf(rm1, C2, sc2.y);
    n = fmaf(rinv, fmaf(rinv, n, BB), sc2.x);
    hvr[2].x = rinv * s.x; hvr[2].y = rinv * s.y;
    hvr[2].z = rinv * s.z; hvr[2].w = rinv * s.w;
    h4[(size_t)SLOT4C * 2 + idx4] = hvr[2];
    s.x = hvr[2].x + w[2].x; s.y = hvr[2].y + w[2].y;
    s.z = hvr[2].z + w[2].z; s.w = hvr[2].w + w[2].w;
    pp = dpp_sum_reg(dot4(hvr[2], w[7]));  // G_7 partial
    SILOUT(hvr[2], 2)
    w[2] = h4[(size_t)SLOT4C * 19 + idx4];  // W_18
    rm2 = rm1; rm1 = rinv;
    BAR0
  }
  // ---- step 3
  {
    if (lane == 63) Gp[3][wave] = pp;  // target 7
    const float rinv = fast_rsq(fmaf(n, INVD, EPSV));
    const float BB = fmaf(rm1, fmaf(rm2, C3, sc3.z), sc3.y);
    n = fmaf(rinv, fmaf(rinv, n, BB), sc3.x);
    hvr[3].x = rinv * s.x; hvr[3].y = rinv * s.y;
    hvr[3].z = rinv * s.z; hvr[3].w = rinv * s.w;
    h4[(size_t)SLOT4C * 3 + idx4] = hvr[3];
    s.x = hvr[3].x + w[3].x; s.y = hvr[3].y + w[3].y;
    s.z = hvr[3].z + w[3].z; s.w = hvr[3].w + w[3].w;
    pp = dpp_sum_reg(dot4(hvr[3], w[8]));  // G_8 partial
    SILOUT(hvr[3], 3)
    w[3] = h4[(size_t)SLOT4C * 20 + idx4];  // W_19
    rm3 = rm2; rm2 = rm1; rm1 = rinv;
    BAR0
  }
  // ---- step 4
  {
    if (lane == 63) Gp[0][wave] = pp;  // target 8
    const float rinv = fast_rsq(fmaf(n, INVD, EPSV));
    const float BB = fmaf(rm1, fmaf(rm2, fmaf(rm3, C4, sc4.w), sc4.z), sc4.y);
    n = fmaf(rinv, fmaf(rinv, n, BB), sc4.x);
    rv = *(const float4*)&Gp[2][0];  // target-6 partials
    hvr[0].x = rinv * s.x; hvr[0].y = rinv * s.y;
    hvr[0].z = rinv * s.z; hvr[0].w = rinv * s.w;
    h4[(size_t)SLOT4C * 4 + idx4] = hvr[0];
    s.x = hvr[0].x + w[4].x; s.y = hvr[0].y + w[4].y;
    s.z = hvr[0].z + w[4].z; s.w = hvr[0].w + w[4].w;
    pp = dpp_sum_reg(dot4(hvr[0], w[9]));  // G_9 partial
    SILOUT(hvr[0], 4)
    w[4] = h4[(size_t)SLOT4C * 21 + idx4];  // W_20
    rm4 = rm3; rm3 = rm2; rm2 = rm1; rm1 = rinv;
    BAR0
  }
  // ---- step 5
  {
    if (lane == 63) Gp[1][wave] = pp;  // target 9
    const float rinv = fast_rsq(fmaf(n, INVD, EPSV));
    const float BB =
        fmaf(rm1, fmaf(rm2, fmaf(rm3, fmaf(rm4, C5, D45x), sc5.w), sc5.z), sc5.y);
    n = fmaf(rinv, fmaf(rinv, n, BB), sc5.x);
    { float gt = (rv.x + rv.y) + (rv.z + rv.w); gr0 = gt + gt; }  // 2*G_6
    rv = *(const float4*)&Gp[3][0];  // target-7 partials
    hvr[1].x = rinv * s.x; hvr[1].y = rinv * s.y;
    hvr[1].z = rinv * s.z; hvr[1].w = rinv * s.w;
    h4[(size_t)SLOT4C * 5 + idx4] = hvr[1];
    s.x = hvr[1].x + w[5].x; s.y = hvr[1].y + w[5].y;
    s.z = hvr[1].z + w[5].z; s.w = hvr[1].w + w[5].w;
    pp = dpp_sum_reg(dot4(hvr[1], w[10]));  // G_10 partial
    SILOUT(hvr[1], 5)
    w[5] = h4[(size_t)SLOT4C * 22 + idx4];  // W_21
    rm4 = rm3; rm3 = rm2; rm2 = rm1; rm1 = rinv;
    BAR0
  }

// Steady step i>=6 (r7 schedule + fused silu store).
#define STEP(I_, WS, W5S, GW, GR, SCR, D45R, GRU, GRW, HVI, BAR_)                    \
  {                                                                                  \
    const int i_ = (I_);                                                             \
    if (lane == 63) Gp[GW][wave] = pp;                                               \
    { float gt_ = (rv.x + rv.y) + (rv.z + rv.w); GRW = gt_ + gt_; }                  \
    rv = *(const float4*)&Gp[GR][0];                                                 \
    const float rinv = fast_rsq(fmaf(n, INVD, EPSV));                                \
    const float BB = fmaf(                                                           \
        rm1, fmaf(rm2, fmaf(rm3, fmaf(rm4, (D45R).y + (GRU), (D45R).x), (SCR).w),    \
                  (SCR).z), (SCR).y);                                                \
    n = fmaf(rinv, fmaf(rinv, n, BB), (SCR).x);                                      \
    hvr[HVI].x = rinv * s.x; hvr[HVI].y = rinv * s.y;                                \
    hvr[HVI].z = rinv * s.z; hvr[HVI].w = rinv * s.w;                                \
    h4[(size_t)SLOT4C * i_ + idx4] = hvr[HVI];                                       \
    s.x = hvr[HVI].x + w[WS].x; s.y = hvr[HVI].y + w[WS].y;                          \
    s.z = hvr[HVI].z + w[WS].z; s.w = hvr[HVI].w + w[WS].w;                          \
    pp = dpp_sum_reg(dot4(hvr[HVI], w[W5S]));                                        \
    SILOUT(hvr[HVI], i_)                                                             \
    const int ipf_ = (i_ + 16 < T_STEPS) ? (i_ + 16) : (T_STEPS - 1);                \
    w[WS] = h4[(size_t)SLOT4C * (ipf_ + 1) + idx4];                                  \
    const int isc_ = (i_ + 2 < T_STEPS) ? (i_ + 2) : (T_STEPS - 1);                  \
    SCR = scLDS[isc_];                                                               \
    D45R = d45LDS[isc_];                                                             \
    rm4 = rm3; rm3 = rm2; rm2 = rm1; rm1 = rinv;                                     \
    if (BAR_) { asm volatile("s_waitcnt lgkmcnt(3)" ::: "memory");                   \
                __builtin_amdgcn_s_barrier(); }                                      \
  }

  // main loop: i = 6..2037 in chunks of 16 (ii ≡ 6 mod 16); HVI = i&3
  for (int ii = 6; ii < 2038; ii += 16) {
    STEP(ii + 0,  6, 11, 2, 0, scA, d45A, gr0, gr1, 2, 0)
    STEP(ii + 1,  7, 12, 3, 1, scB, d45B, gr1, gr0, 3, 1)
    STEP(ii + 2,  8, 13, 0, 2, scA, d45A, gr0, gr1, 0, 0)
    STEP(ii + 3,  9, 14, 1, 3, scB, d45B, gr1, gr0, 1, 1)
    STEP(ii + 4, 10, 15, 2, 0, scA, d45A, gr0, gr1, 2, 0)
    STEP(ii + 5, 11,  0, 3, 1, scB, d45B, gr1, gr0, 3, 1)
    STEP(ii + 6, 12,  1, 0, 2, scA, d45A, gr0, gr1, 0, 0)
    STEP(ii + 7, 13,  2, 1, 3, scB, d45B, gr1, gr0, 1, 1)
    STEP(ii + 8, 14,  3, 2, 0, scA, d45A, gr0, gr1, 2, 0)
    STEP(ii + 9, 15,  4, 3, 1, scB, d45B, gr1, gr0, 3, 1)
    STEP(ii + 10, 0,  5, 0, 2, scA, d45A, gr0, gr1, 0, 0)
    STEP(ii + 11, 1,  6, 1, 3, scB, d45B, gr1, gr0, 1, 1)
    STEP(ii + 12, 2,  7, 2, 0, scA, d45A, gr0, gr1, 2, 0)
    STEP(ii + 13, 3,  8, 3, 1, scB, d45B, gr1, gr0, 3, 1)
    STEP(ii + 14, 4,  9, 0, 2, scA, d45A, gr0, gr1, 0, 0)
    STEP(ii + 15, 5, 10, 1, 3, scB, d45B, gr1, gr0, 1, 1)
  }
  // tail: i = 2038..2047 (continues pattern, 2038 ≡ 6 mod 16)
  STEP(2038,  6, 11, 2, 0, scA, d45A, gr0, gr1, 2, 0)
  STEP(2039,  7, 12, 3, 1, scB, d45B, gr1, gr0, 3, 1)
  STEP(2040,  8, 13, 0, 2, scA, d45A, gr0, gr1, 0, 0)
  STEP(2041,  9, 14, 1, 3, scB, d45B, gr1, gr0, 1, 1)
  STEP(2042, 10, 15, 2, 0, scA, d45A, gr0, gr1, 2, 0)
  STEP(2043, 11,  0, 3, 1, scB, d45B, gr1, gr0, 3, 1)
  STEP(2044, 12,  1, 0, 2, scA, d45A, gr0, gr1, 0, 0)
  STEP(2045, 13,  2, 1, 3, scB, d45B, gr1, gr0, 1, 1)
  STEP(2046, 14,  3, 2, 0, scA, d45A, gr0, gr1, 2, 0)
  STEP(2047, 15,  4, 3, 1, scB, d45B, gr1, gr0, 3, 1)
#undef STEP
#undef BAR0

  // final: h_2048 = rinv * s -> slot 2048 ; out slot 2047
  const float rinvT = fast_rsq(fmaf(n, INVD, EPSV));
  float4 o;
  o.x = rinvT * s.x; o.y = rinvT * s.y; o.z = rinvT * s.z; o.w = rinvT * s.w;
  h4[(size_t)SLOT4C * T_STEPS + idx4] = o;
  SILOUT(o, T_STEPS)
#undef SILOUT
}

extern "C" void kernel_launch(void* const* d_in, const int* in_sizes, int n_in,
                              void* d_out, int out_size, void* d_ws, size_t ws_size,
                              hipStream_t stream) {
  (void)in_sizes; (void)n_in; (void)d_ws; (void)ws_size; (void)out_size;
  const float* x = (const float*)d_in[0];
  const float* h0 = (const float*)d_in[1];
  const float* W = (const float*)d_in[2];
  const float* bias = (const float*)d_in[3];
  const float* log_alpha = (const float*)d_in[4];

  float* out = (float*)d_out;                               // outs region [T][B][D]
  float* hreg = out + (size_t)T_STEPS * BATCH * DIM;        // h region [T+1][B][D]
  // staging overlays the outs region (consumed before scan overwrites it; see
  // scan_kernel header for the scal4/d45g race-window argument)
  __hip_bfloat16* xb = (__hip_bfloat16*)d_out;
  __hip_bfloat16* wb = (__hip_bfloat16*)((char*)d_out + (size_t)T_STEPS * BATCH * DIM * 2);
  float4* scal4 = (float4*)(out + (size_t)26 * 1024 * 1024);  // 104 MB offset
  float2* d45g = (float2*)(out + (size_t)27 * 1024 * 1024);   // 108 MB offset

  const int nx8 = T_STEPS * BATCH * DIM / 8;
  const int nw8 = DIM * DIM / 8;
  cvt_kernel<<<nx8 / 256, 256, 0, stream>>>(x, (bf16x8pack*)xb, nx8);
  cvt_kernel<<<nw8 / 256, 256, 0, stream>>>(W, (bf16x8pack*)wb, nw8);

  dim3 ggrid(DIM / 128, (T_STEPS * BATCH) / 128);
  gemm_kernel<<<ggrid, 256, 0, stream>>>(xb, wb, bias, log_alpha, hreg);

  dots_kernel<<<T_STEPS * BATCH, 64, 0, stream>>>(hreg, scal4, d45g);

  scan_kernel<<<BATCH, 256, 0, stream>>>(h0, scal4, d45g, hreg, out);
}

// Round 15
// 530.924 us; speedup vs baseline: 1.3302x; 1.1284x over previous
//
#include <hip/hip_runtime.h>
#include <hip/hip_bf16.h>

#define T_STEPS 2048
#define BATCH 16
#define DIM 1024
#define EPSV 1e-6f
#define INVD (1.0f / 1024.0f)
#define SLOTF (BATCH * DIM)      // floats per [B][D] slot
#define SLOT4C (BATCH * DIM / 4) // float4 per slot

typedef short short8 __attribute__((ext_vector_type(8)));
typedef float f32x4 __attribute__((ext_vector_type(4)));

struct alignas(16) bf16x8pack { __hip_bfloat16 v[8]; };

__device__ __forceinline__ float dot4(const float4& a, const float4& c) {
  return fmaf(a.x, c.x, fmaf(a.y, c.y, fmaf(a.z, c.z, a.w * c.w)));
}
__device__ __forceinline__ float fast_rsq(float x) {
  float r;
  asm("v_rsq_f32 %0, %1" : "=v"(r) : "v"(x));
  return r;
}

// ---------------- fp32 -> bf16 convert (vectorized) ----------------
__global__ __launch_bounds__(256) void cvt_kernel(const float* __restrict__ src,
                                                  bf16x8pack* __restrict__ dst, int n8) {
  int i = blockIdx.x * blockDim.x + threadIdx.x;
  if (i >= n8) return;
  const float4* s4 = (const float4*)src + (size_t)i * 2;
  float4 a = s4[0];
  float4 b = s4[1];
  bf16x8pack p;
  p.v[0] = __float2bfloat16(a.x); p.v[1] = __float2bfloat16(a.y);
  p.v[2] = __float2bfloat16(a.z); p.v[3] = __float2bfloat16(a.w);
  p.v[4] = __float2bfloat16(b.x); p.v[5] = __float2bfloat16(b.y);
  p.v[6] = __float2bfloat16(b.z); p.v[7] = __float2bfloat16(b.w);
  dst[i] = p;
}

// ---------------- bf16 MFMA GEMM: out[m][e] = alpha*(sum_d X[m][d]*W[e][d] + b[e]) ----
__global__ __launch_bounds__(256) void gemm_kernel(
    const __hip_bfloat16* __restrict__ Xb,
    const __hip_bfloat16* __restrict__ Wb,
    const float* __restrict__ bias,
    const float* __restrict__ log_alpha_p,
    float* __restrict__ hreg) {
  __shared__ __hip_bfloat16 As[128 * 32];
  __shared__ __hip_bfloat16 Bs[128 * 32];
  const int tid = threadIdx.x;
  const int wave = tid >> 6, lane = tid & 63;
  const int m0 = blockIdx.y * 128;
  const int e0 = blockIdx.x * 128;
  const int wm = (wave >> 1) * 64;
  const int wn = (wave & 1) * 64;
  const int l15 = lane & 15, l4 = lane >> 4;

  f32x4 acc[4][4] = {};

  const int srow = wave * 16 + (lane >> 2);
  const int sch = (lane & 3) * 8;

  for (int kt = 0; kt < DIM; kt += 32) {
    __syncthreads();
#pragma unroll
    for (int i = 0; i < 2; ++i) {
      const __hip_bfloat16* ga = Xb + (size_t)(m0 + i * 64 + srow) * DIM + kt + sch;
      const __hip_bfloat16* gb = Wb + (size_t)(e0 + i * 64 + srow) * DIM + kt + sch;
      __builtin_amdgcn_global_load_lds(
          (const __attribute__((address_space(1))) void*)ga,
          (__attribute__((address_space(3))) void*)((char*)As + (i * 64 + wave * 16) * 64),
          16, 0, 0);
      __builtin_amdgcn_global_load_lds(
          (const __attribute__((address_space(1))) void*)gb,
          (__attribute__((address_space(3))) void*)((char*)Bs + (i * 64 + wave * 16) * 64),
          16, 0, 0);
    }
    __syncthreads();
    short8 a[4], b[4];
#pragma unroll
    for (int f = 0; f < 4; ++f)
      a[f] = *(const short8*)((const char*)As + ((wm + f * 16 + l15) * 32 + l4 * 8) * 2);
#pragma unroll
    for (int g = 0; g < 4; ++g)
      b[g] = *(const short8*)((const char*)Bs + ((wn + g * 16 + l15) * 32 + l4 * 8) * 2);
#pragma unroll
    for (int f = 0; f < 4; ++f)
#pragma unroll
      for (int g = 0; g < 4; ++g)
        acc[f][g] = __builtin_amdgcn_mfma_f32_16x16x32_bf16(a[f], b[g], acc[f][g], 0, 0, 0);
  }
  const float alpha = __expf(log_alpha_p[0]);
#pragma unroll
  for (int g = 0; g < 4; ++g) {
    const int e = e0 + wn + g * 16 + l15;
    const float bv = bias[e];
#pragma unroll
    for (int f = 0; f < 4; ++f) {
#pragma unroll
      for (int r = 0; r < 4; ++r) {
        const int m = m0 + wm + f * 16 + l4 * 4 + r;
        hreg[(size_t)(m + BATCH) * DIM + e] = alpha * (acc[f][g][r] + bv);
      }
    }
  }
}

// ---------------- DPP wave-sum helper (total lands in lane 63) ----------------
__device__ __forceinline__ float dpp_sum_reg(float x) {
  float acc = x;
#define DPP_ADD(ctrl)                                                              \
  {                                                                                \
    int t_ = __builtin_amdgcn_update_dpp(0, __float_as_int(acc), (ctrl), 0xf, 0xf, \
                                         true);                                    \
    acc += __int_as_float(t_);                                                     \
  }
  DPP_ADD(0x111); DPP_ADD(0x112); DPP_ADD(0x114); DPP_ADD(0x118);
  DPP_ADD(0x142); DPP_ADD(0x143);
#undef DPP_ADD
  return acc;
}

// ---- precompute: scal4[t]=(e, 2d, 2d2, 2d3), d45[t]=(2d4, 2d5)  (dk = W_{t-k}.W_t)
// TILED (r15): one block computes 8 consecutive t for one batch row, holding the
// 13-row sliding window in registers (208 VGPR) -> 3.7x less read traffic and
// 8x fewer blocks than the per-(t,b) version. Row slots needed for t in
// [t0,t0+7]: t0-4 .. t0+8 -> R[k] = slot (t0-4+k), k=0..12 (clamped >=0; the
// clamped rows feed only guarded (t<k) terms, which are zeroed before write).
__global__ __launch_bounds__(64, 1) void dots_kernel(const float* __restrict__ hreg,
                                                     float4* __restrict__ scal4,
                                                     float2* __restrict__ d45g) {
  const int tile = blockIdx.x >> 4;   // 256 tiles of 8 t-values
  const int b = blockIdx.x & 15;
  const int t0 = tile * 8;
  const int lane = threadIdx.x;
  const float4* h4 = (const float4*)hreg;

  float4 R[13][4];
#pragma unroll
  for (int k = 0; k < 13; ++k) {
    int si = t0 - 4 + k;            // slot index (W_{si-1} lives at slot si)
    if (si < 0) si = 0;             // tile 0 only; values discarded by guards
#pragma unroll
    for (int j = 0; j < 4; ++j)
      R[k][j] = h4[(size_t)si * SLOT4C + b * 256 + lane + 64 * j];
  }

#pragma unroll
  for (int u = 0; u < 8; ++u) {
    const int t = t0 + u;
    float e = 0.f, d = 0.f, d2 = 0.f, d3 = 0.f, d4 = 0.f, d5 = 0.f;
#pragma unroll
    for (int j = 0; j < 4; ++j) {
      const float4 a = R[u + 5][j];   // W_t       (slot t+1)
      e = fmaf(a.x, a.x, fmaf(a.y, a.y, fmaf(a.z, a.z, fmaf(a.w, a.w, e))));
      const float4 p1 = R[u + 4][j];  // W_{t-1}
      d = fmaf(p1.x, a.x, fmaf(p1.y, a.y, fmaf(p1.z, a.z, fmaf(p1.w, a.w, d))));
      const float4 p2 = R[u + 3][j];  // W_{t-2}
      d2 = fmaf(p2.x, a.x, fmaf(p2.y, a.y, fmaf(p2.z, a.z, fmaf(p2.w, a.w, d2))));
      const float4 p3 = R[u + 2][j];  // W_{t-3}
      d3 = fmaf(p3.x, a.x, fmaf(p3.y, a.y, fmaf(p3.z, a.z, fmaf(p3.w, a.w, d3))));
      const float4 p4 = R[u + 1][j];  // W_{t-4}
      d4 = fmaf(p4.x, a.x, fmaf(p4.y, a.y, fmaf(p4.z, a.z, fmaf(p4.w, a.w, d4))));
      const float4 p5 = R[u][j];      // W_{t-5}
      d5 = fmaf(p5.x, a.x, fmaf(p5.y, a.y, fmaf(p5.z, a.z, fmaf(p5.w, a.w, d5))));
    }
    e = dpp_sum_reg(e);
    d = dpp_sum_reg(d);
    d2 = dpp_sum_reg(d2);
    d3 = dpp_sum_reg(d3);
    d4 = dpp_sum_reg(d4);
    d5 = dpp_sum_reg(d5);
    if (lane == 63) {
      const float dd  = (t >= 1) ? d + d : 0.f;
      const float dd2 = (t >= 2) ? d2 + d2 : 0.f;
      const float dd3 = (t >= 3) ? d3 + d3 : 0.f;
      const float dd4 = (t >= 4) ? d4 + d4 : 0.f;
      const float dd5 = (t >= 5) ? d5 + d5 : 0.f;
      scal4[b * T_STEPS + t] = make_float4(e, dd, dd2, dd3);
      d45g[b * T_STEPS + t] = make_float2(dd4, dd5);
    }
  }
}

// ---------------- sequential scan, 4 waves/row, depth-5 pipeline (r7, 323us) -----
// s_{i+1}=h_i+W_i, h_i=rinv_i*s_i, n_{i+1}=rinv^2 n + 2 rinv b_i + e_i,
// 2b_i = 2d + r1(2d2 + r2(2d3 + r3(2d4 + r4(2d5 + 2G)))), G_i = h_{i-5}.W_i.
// 4-deep hv store ring; barrier every 2 steps with counted lgkmcnt(3).
__global__ __launch_bounds__(256, 1) void scan_kernel(
    const float* __restrict__ h0,
    const float4* __restrict__ scal4,
    const float2* __restrict__ d45g,
    float* __restrict__ hreg) {
  const int b = blockIdx.x;
  const int tid = threadIdx.x;
  const int wave = tid >> 6;
  const int lane = tid & 63;
  float4* h4 = (float4*)hreg;
  const int idx4 = b * 256 + tid;

  __shared__ float4 scLDS[T_STEPS];          // 32 KB
  __shared__ float2 d45LDS[T_STEPS];         // 16 KB
  __shared__ alignas(16) float Gp[4][4];     // [target&3][wave]
  __shared__ float initP[4][6];

#pragma unroll
  for (int p = 0; p < 8; ++p)
    scLDS[p * 256 + tid] = scal4[b * T_STEPS + p * 256 + tid];
#pragma unroll
  for (int p = 0; p < 8; ++p)
    d45LDS[p * 256 + tid] = d45g[b * T_STEPS + p * 256 + tid];

  // W ring-16: w[k] = W_k for k=2..15, w[0]=W_16, w[1]=W_17  (W_j at hreg slot j+1)
  float4 w[16];
#pragma unroll
  for (int k = 2; k < 16; ++k) w[k] = h4[(size_t)SLOT4C * (k + 1) + idx4];
  w[0] = h4[(size_t)SLOT4C * 17 + idx4];
  w[1] = h4[(size_t)SLOT4C * 18 + idx4];
  float4 w0v = h4[(size_t)SLOT4C * 1 + idx4];  // W_0
  float4 w1v = h4[(size_t)SLOT4C * 2 + idx4];  // W_1
  float4 h0v = ((const float4*)h0)[idx4];
  h4[idx4] = h0v;  // slot 0 = h_0

  // startup direct reductions off s_1 = h_0 + W_0
  float4 s;
  s.x = h0v.x + w0v.x; s.y = h0v.y + w0v.y;
  s.z = h0v.z + w0v.z; s.w = h0v.w + w0v.w;
  {
    float q  = dpp_sum_reg(dot4(s, s));
    float r  = dpp_sum_reg(dot4(s, w1v));
    float c2 = dpp_sum_reg(dot4(s, w[2]));
    float c3 = dpp_sum_reg(dot4(s, w[3]));
    float c4 = dpp_sum_reg(dot4(s, w[4]));
    float c5 = dpp_sum_reg(dot4(s, w[5]));
    if (lane == 63) {
      initP[wave][0] = q;  initP[wave][1] = r;  initP[wave][2] = c2;
      initP[wave][3] = c3; initP[wave][4] = c4; initP[wave][5] = c5;
    }
  }
  __syncthreads();
  const float n1 = (initP[0][0] + initP[1][0]) + (initP[2][0] + initP[3][0]);
  float t1 = (initP[0][1] + initP[1][1]) + (initP[2][1] + initP[3][1]);
  float t2 = (initP[0][2] + initP[1][2]) + (initP[2][2] + initP[3][2]);
  float t3 = (initP[0][3] + initP[1][3]) + (initP[2][3] + initP[3][3]);
  float t4 = (initP[0][4] + initP[1][4]) + (initP[2][4] + initP[3][4]);
  float t5 = (initP[0][5] + initP[1][5]) + (initP[2][5] + initP[3][5]);
  const float B1 = t1 + t1, C2 = t2 + t2, C3 = t3 + t3, C4 = t4 + t4, C5 = t5 + t5;

  const float e1 = scLDS[1].x;
  float4 sc2 = scLDS[2], sc3 = scLDS[3], sc4 = scLDS[4], sc5 = scLDS[5];
  const float D45x = d45LDS[5].x;  // 2*d4_5
  float4 scA = scLDS[6], scB = scLDS[7];
  float2 d45A = d45LDS[6], d45B = d45LDS[7];

  float n = n1, rm1, rm2, rm3, rm4, pp;
  float gr0 = 0.f, gr1 = 0.f;
  float4 rv = make_float4(0.f, 0.f, 0.f, 0.f);
  float4 hvr[4];  // store-data register ring (static indices)

#define BAR0 { asm volatile("s_waitcnt lgkmcnt(0)" ::: "memory"); __builtin_amdgcn_s_barrier(); }

  // ---- step 1
  {
    const float rinv = fast_rsq(fmaf(n, INVD, EPSV));
    n = fmaf(rinv, fmaf(rinv, n, B1), e1);
    hvr[1].x = rinv * s.x; hvr[1].y = rinv * s.y;
    hvr[1].z = rinv * s.z; hvr[1].w = rinv * s.w;
    h4[(size_t)SLOT4C * 1 + idx4] = hvr[1];
    s.x = hvr[1].x + w1v.x; s.y = hvr[1].y + w1v.y;
    s.z = hvr[1].z + w1v.z; s.w = hvr[1].w + w1v.w;
    pp = dpp_sum_reg(dot4(hvr[1], w[6]));  // G_6 partial
    rm1 = rinv;
    BAR0
  }
  // ---- step 2
  {
    if (lane == 63) Gp[2][wave] = pp;  // target 6
    const float rinv = fast_rsq(fmaf(n, INVD, EPSV));
    const float BB = fmaf(rm1, C2, sc2.y);
    n = fmaf(rinv, fmaf(rinv, n, BB), sc2.x);
    hvr[2].x = rinv * s.x; hvr[2].y = rinv * s.y;
    hvr[2].z = rinv * s.z; hvr[2].w = rinv * s.w;
    h4[(size_t)SLOT4C * 2 + idx4] = hvr[2];
    s.x = hvr[2].x + w[2].x; s.y = hvr[2].y + w[2].y;
    s.z = hvr[2].z + w[2].z; s.w = hvr[2].w + w[2].w;
    pp = dpp_sum_reg(dot4(hvr[2], w[7]));  // G_7 partial
    w[2] = h4[(size_t)SLOT4C * 19 + idx4];  // W_18
    rm2 = rm1; rm1 = rinv;
    BAR0
  }
  // ---- step 3
  {
    if (lane == 63) Gp[3][wave] = pp;  // target 7
    const float rinv = fast_rsq(fmaf(n, INVD, EPSV));
    const float BB = fmaf(rm1, fmaf(rm2, C3, sc3.z), sc3.y);
    n = fmaf(rinv, fmaf(rinv, n, BB), sc3.x);
    hvr[3].x = rinv * s.x; hvr[3].y = rinv * s.y;
    hvr[3].z = rinv * s.z; hvr[3].w = rinv * s.w;
    h4[(size_t)SLOT4C * 3 + idx4] = hvr[3];
    s.x = hvr[3].x + w[3].x; s.y = hvr[3].y + w[3].y;
    s.z = hvr[3].z + w[3].z; s.w = hvr[3].w + w[3].w;
    pp = dpp_sum_reg(dot4(hvr[3], w[8]));  // G_8 partial
    w[3] = h4[(size_t)SLOT4C * 20 + idx4];  // W_19
    rm3 = rm2; rm2 = rm1; rm1 = rinv;
    BAR0
  }
  // ---- step 4
  {
    if (lane == 63) Gp[0][wave] = pp;  // target 8
    const float rinv = fast_rsq(fmaf(n, INVD, EPSV));
    const float BB = fmaf(rm1, fmaf(rm2, fmaf(rm3, C4, sc4.w), sc4.z), sc4.y);
    n = fmaf(rinv, fmaf(rinv, n, BB), sc4.x);
    rv = *(const float4*)&Gp[2][0];  // target-6 partials
    hvr[0].x = rinv * s.x; hvr[0].y = rinv * s.y;
    hvr[0].z = rinv * s.z; hvr[0].w = rinv * s.w;
    h4[(size_t)SLOT4C * 4 + idx4] = hvr[0];
    s.x = hvr[0].x + w[4].x; s.y = hvr[0].y + w[4].y;
    s.z = hvr[0].z + w[4].z; s.w = hvr[0].w + w[4].w;
    pp = dpp_sum_reg(dot4(hvr[0], w[9]));  // G_9 partial
    w[4] = h4[(size_t)SLOT4C * 21 + idx4];  // W_20
    rm4 = rm3; rm3 = rm2; rm2 = rm1; rm1 = rinv;
    BAR0
  }
  // ---- step 5
  {
    if (lane == 63) Gp[1][wave] = pp;  // target 9
    const float rinv = fast_rsq(fmaf(n, INVD, EPSV));
    const float BB =
        fmaf(rm1, fmaf(rm2, fmaf(rm3, fmaf(rm4, C5, D45x), sc5.w), sc5.z), sc5.y);
    n = fmaf(rinv, fmaf(rinv, n, BB), sc5.x);
    { float gt = (rv.x + rv.y) + (rv.z + rv.w); gr0 = gt + gt; }  // 2*G_6
    rv = *(const float4*)&Gp[3][0];  // target-7 partials
    hvr[1].x = rinv * s.x; hvr[1].y = rinv * s.y;
    hvr[1].z = rinv * s.z; hvr[1].w = rinv * s.w;
    h4[(size_t)SLOT4C * 5 + idx4] = hvr[1];
    s.x = hvr[1].x + w[5].x; s.y = hvr[1].y + w[5].y;
    s.z = hvr[1].z + w[5].z; s.w = hvr[1].w + w[5].w;
    pp = dpp_sum_reg(dot4(hvr[1], w[10]));  // G_10 partial
    w[5] = h4[(size_t)SLOT4C * 22 + idx4];  // W_21
    rm4 = rm3; rm3 = rm2; rm2 = rm1; rm1 = rinv;
    BAR0
  }

// Steady step i>=6 (r7 schedule).
#define STEP(I_, WS, W5S, GW, GR, SCR, D45R, GRU, GRW, HVI, BAR_)                    \
  {                                                                                  \
    const int i_ = (I_);                                                             \
    if (lane == 63) Gp[GW][wave] = pp;                                               \
    { float gt_ = (rv.x + rv.y) + (rv.z + rv.w); GRW = gt_ + gt_; }                  \
    rv = *(const float4*)&Gp[GR][0];                                                 \
    const float rinv = fast_rsq(fmaf(n, INVD, EPSV));                                \
    const float BB = fmaf(                                                           \
        rm1, fmaf(rm2, fmaf(rm3, fmaf(rm4, (D45R).y + (GRU), (D45R).x), (SCR).w),    \
                  (SCR).z), (SCR).y);                                                \
    n = fmaf(rinv, fmaf(rinv, n, BB), (SCR).x);                                      \
    hvr[HVI].x = rinv * s.x; hvr[HVI].y = rinv * s.y;                                \
    hvr[HVI].z = rinv * s.z; hvr[HVI].w = rinv * s.w;                                \
    h4[(size_t)SLOT4C * i_ + idx4] = hvr[HVI];                                       \
    s.x = hvr[HVI].x + w[WS].x; s.y = hvr[HVI].y + w[WS].y;                          \
    s.z = hvr[HVI].z + w[WS].z; s.w = hvr[HVI].w + w[WS].w;                          \
    pp = dpp_sum_reg(dot4(hvr[HVI], w[W5S]));                                        \
    const int ipf_ = (i_ + 16 < T_STEPS) ? (i_ + 16) : (T_STEPS - 1);                \
    w[WS] = h4[(size_t)SLOT4C * (ipf_ + 1) + idx4];                                  \
    const int isc_ = (i_ + 2 < T_STEPS) ? (i_ + 2) : (T_STEPS - 1);                  \
    SCR = scLDS[isc_];                                                               \
    D45R = d45LDS[isc_];                                                             \
    rm4 = rm3; rm3 = rm2; rm2 = rm1; rm1 = rinv;                                     \
    if (BAR_) { asm volatile("s_waitcnt lgkmcnt(3)" ::: "memory");                   \
                __builtin_amdgcn_s_barrier(); }                                      \
  }

  // main loop: i = 6..2037 in chunks of 16 (ii ≡ 6 mod 16); HVI = i&3
  for (int ii = 6; ii < 2038; ii += 16) {
    STEP(ii + 0,  6, 11, 2, 0, scA, d45A, gr0, gr1, 2, 0)
    STEP(ii + 1,  7, 12, 3, 1, scB, d45B, gr1, gr0, 3, 1)
    STEP(ii + 2,  8, 13, 0, 2, scA, d45A, gr0, gr1, 0, 0)
    STEP(ii + 3,  9, 14, 1, 3, scB, d45B, gr1, gr0, 1, 1)
    STEP(ii + 4, 10, 15, 2, 0, scA, d45A, gr0, gr1, 2, 0)
    STEP(ii + 5, 11,  0, 3, 1, scB, d45B, gr1, gr0, 3, 1)
    STEP(ii + 6, 12,  1, 0, 2, scA, d45A, gr0, gr1, 0, 0)
    STEP(ii + 7, 13,  2, 1, 3, scB, d45B, gr1, gr0, 1, 1)
    STEP(ii + 8, 14,  3, 2, 0, scA, d45A, gr0, gr1, 2, 0)
    STEP(ii + 9, 15,  4, 3, 1, scB, d45B, gr1, gr0, 3, 1)
    STEP(ii + 10, 0,  5, 0, 2, scA, d45A, gr0, gr1, 0, 0)
    STEP(ii + 11, 1,  6, 1, 3, scB, d45B, gr1, gr0, 1, 1)
    STEP(ii + 12, 2,  7, 2, 0, scA, d45A, gr0, gr1, 2, 0)
    STEP(ii + 13, 3,  8, 3, 1, scB, d45B, gr1, gr0, 3, 1)
    STEP(ii + 14, 4,  9, 0, 2, scA, d45A, gr0, gr1, 0, 0)
    STEP(ii + 15, 5, 10, 1, 3, scB, d45B, gr1, gr0, 1, 1)
  }
  // tail: i = 2038..2047 (continues pattern, 2038 ≡ 6 mod 16)
  STEP(2038,  6, 11, 2, 0, scA, d45A, gr0, gr1, 2, 0)
  STEP(2039,  7, 12, 3, 1, scB, d45B, gr1, gr0, 3, 1)
  STEP(2040,  8, 13, 0, 2, scA, d45A, gr0, gr1, 0, 0)
  STEP(2041,  9, 14, 1, 3, scB, d45B, gr1, gr0, 1, 1)
  STEP(2042, 10, 15, 2, 0, scA, d45A, gr0, gr1, 2, 0)
  STEP(2043, 11,  0, 3, 1, scB, d45B, gr1, gr0, 3, 1)
  STEP(2044, 12,  1, 0, 2, scA, d45A, gr0, gr1, 0, 0)
  STEP(2045, 13,  2, 1, 3, scB, d45B, gr1, gr0, 1, 1)
  STEP(2046, 14,  3, 2, 0, scA, d45A, gr0, gr1, 2, 0)
  STEP(2047, 15,  4, 3, 1, scB, d45B, gr1, gr0, 3, 1)
#undef STEP
#undef BAR0

  // final: h_2048 = rinv * s -> slot 2048
  const float rinvT = fast_rsq(fmaf(n, INVD, EPSV));
  float4 o;
  o.x = rinvT * s.x; o.y = rinvT * s.y; o.z = rinvT * s.z; o.w = rinvT * s.w;
  h4[(size_t)SLOT4C * T_STEPS + idx4] = o;
}

// ---------------- outs[t] = h_{t+1} * silu(h_{t+1}) ----------------
__global__ __launch_bounds__(256) void silu_kernel(const float4* __restrict__ hsrc,
                                                   float4* __restrict__ out4, int n4) {
  int i = blockIdx.x * blockDim.x + threadIdx.x;
  if (i >= n4) return;
  float4 h = hsrc[i];
  float4 o;
  o.x = h.x * h.x / (1.f + __expf(-h.x));
  o.y = h.y * h.y / (1.f + __expf(-h.y));
  o.z = h.z * h.z / (1.f + __expf(-h.z));
  o.w = h.w * h.w / (1.f + __expf(-h.w));
  out4[i] = o;
}

extern "C" void kernel_launch(void* const* d_in, const int* in_sizes, int n_in,
                              void* d_out, int out_size, void* d_ws, size_t ws_size,
                              hipStream_t stream) {
  (void)in_sizes; (void)n_in; (void)d_ws; (void)ws_size; (void)out_size;
  const float* x = (const float*)d_in[0];
  const float* h0 = (const float*)d_in[1];
  const float* W = (const float*)d_in[2];
  const float* bias = (const float*)d_in[3];
  const float* log_alpha = (const float*)d_in[4];

  float* out = (float*)d_out;                               // outs region [T][B][D]
  float* hreg = out + (size_t)T_STEPS * BATCH * DIM;        // h region [T+1][B][D]
  // staging overlays the outs region (consumed before scan/silu touch it)
  __hip_bfloat16* xb = (__hip_bfloat16*)d_out;
  __hip_bfloat16* wb = (__hip_bfloat16*)((char*)d_out + (size_t)T_STEPS * BATCH * DIM * 2);
  float4* scal4 = (float4*)(out + (size_t)26 * 1024 * 1024);  // 104 MB offset
  float2* d45g = (float2*)(out + (size_t)27 * 1024 * 1024);   // 108 MB offset

  const int nx8 = T_STEPS * BATCH * DIM / 8;
  const int nw8 = DIM * DIM / 8;
  cvt_kernel<<<nx8 / 256, 256, 0, stream>>>(x, (bf16x8pack*)xb, nx8);
  cvt_kernel<<<nw8 / 256, 256, 0, stream>>>(W, (bf16x8pack*)wb, nw8);

  dim3 ggrid(DIM / 128, (T_STEPS * BATCH) / 128);
  gemm_kernel<<<ggrid, 256, 0, stream>>>(xb, wb, bias, log_alpha, hreg);

  dots_kernel<<<(T_STEPS / 8) * BATCH, 64, 0, stream>>>(hreg, scal4, d45g);

  scan_kernel<<<BATCH, 256, 0, stream>>>(h0, scal4, d45g, hreg);

  const int n4 = T_STEPS * BATCH * DIM / 4;
  silu_kernel<<<n4 / 256, 256, 0, stream>>>((const float4*)(hreg + BATCH * DIM),
                                            (float4*)out, n4);
}

// Round 16
// 511.712 us; speedup vs baseline: 1.3802x; 1.0375x over previous
//
#include <hip/hip_runtime.h>
#include <hip/hip_bf16.h>

#define T_STEPS 2048
#define BATCH 16
#define DIM 1024
#define EPSV 1e-6f
#define INVD (1.0f / 1024.0f)
#define SLOTF (BATCH * DIM)      // floats per [B][D] slot
#define SLOT4C (BATCH * DIM / 4) // float4 per slot

typedef short short8 __attribute__((ext_vector_type(8)));
typedef float f32x4 __attribute__((ext_vector_type(4)));

struct alignas(16) bf16x8pack { __hip_bfloat16 v[8]; };

__device__ __forceinline__ float dot4(const float4& a, const float4& c) {
  return fmaf(a.x, c.x, fmaf(a.y, c.y, fmaf(a.z, c.z, a.w * c.w)));
}
__device__ __forceinline__ float fast_rsq(float x) {
  float r;
  asm("v_rsq_f32 %0, %1" : "=v"(r) : "v"(x));
  return r;
}

// ---------------- fused fp32 -> bf16 convert (x then W, one launch) ----------------
__global__ __launch_bounds__(256) void cvt_kernel(const float* __restrict__ xsrc,
                                                  const float* __restrict__ wsrc,
                                                  bf16x8pack* __restrict__ xdst,
                                                  bf16x8pack* __restrict__ wdst,
                                                  int nx8, int ntot8) {
  int i = blockIdx.x * blockDim.x + threadIdx.x;
  if (i >= ntot8) return;
  const float* src;
  bf16x8pack* dst;
  int k;
  if (i < nx8) { src = xsrc; dst = xdst; k = i; }
  else         { src = wsrc; dst = wdst; k = i - nx8; }
  const float4* s4 = (const float4*)src + (size_t)k * 2;
  float4 a = s4[0];
  float4 b = s4[1];
  bf16x8pack p;
  p.v[0] = __float2bfloat16(a.x); p.v[1] = __float2bfloat16(a.y);
  p.v[2] = __float2bfloat16(a.z); p.v[3] = __float2bfloat16(a.w);
  p.v[4] = __float2bfloat16(b.x); p.v[5] = __float2bfloat16(b.y);
  p.v[6] = __float2bfloat16(b.z); p.v[7] = __float2bfloat16(b.w);
  dst[k] = p;
}

// ---------------- bf16 MFMA GEMM: out[m][e] = alpha*(sum_d X[m][d]*W[e][d] + b[e]) ----
// r16: 1D grid (2048 blocks) with XCD-chunked swizzle (T1): hardware assigns
// XCD = d%8; work = (d&7)*256 + (d>>3) gives each XCD 32 consecutive row-blocks
// x all 8 column tiles -> A-tile 8-fold reuse hits the XCD's own L2 (was: the 8
// column tiles of a row-block round-robined across all 8 XCDs).
__global__ __launch_bounds__(256) void gemm_kernel(
    const __hip_bfloat16* __restrict__ Xb,
    const __hip_bfloat16* __restrict__ Wb,
    const float* __restrict__ bias,
    const float* __restrict__ log_alpha_p,
    float* __restrict__ hreg) {
  __shared__ __hip_bfloat16 As[128 * 32];
  __shared__ __hip_bfloat16 Bs[128 * 32];
  const int tid = threadIdx.x;
  const int wave = tid >> 6, lane = tid & 63;
  const int d = blockIdx.x;
  const int work = ((d & 7) << 8) + (d >> 3);   // bijective on [0,2048)
  const int m0 = (work >> 3) * 128;             // row-block
  const int e0 = (work & 7) * 128;              // column tile
  const int wm = (wave >> 1) * 64;
  const int wn = (wave & 1) * 64;
  const int l15 = lane & 15, l4 = lane >> 4;

  f32x4 acc[4][4] = {};

  const int srow = wave * 16 + (lane >> 2);
  const int sch = (lane & 3) * 8;

  for (int kt = 0; kt < DIM; kt += 32) {
    __syncthreads();
#pragma unroll
    for (int i = 0; i < 2; ++i) {
      const __hip_bfloat16* ga = Xb + (size_t)(m0 + i * 64 + srow) * DIM + kt + sch;
      const __hip_bfloat16* gb = Wb + (size_t)(e0 + i * 64 + srow) * DIM + kt + sch;
      __builtin_amdgcn_global_load_lds(
          (const __attribute__((address_space(1))) void*)ga,
          (__attribute__((address_space(3))) void*)((char*)As + (i * 64 + wave * 16) * 64),
          16, 0, 0);
      __builtin_amdgcn_global_load_lds(
          (const __attribute__((address_space(1))) void*)gb,
          (__attribute__((address_space(3))) void*)((char*)Bs + (i * 64 + wave * 16) * 64),
          16, 0, 0);
    }
    __syncthreads();
    short8 a[4], b[4];
#pragma unroll
    for (int f = 0; f < 4; ++f)
      a[f] = *(const short8*)((const char*)As + ((wm + f * 16 + l15) * 32 + l4 * 8) * 2);
#pragma unroll
    for (int g = 0; g < 4; ++g)
      b[g] = *(const short8*)((const char*)Bs + ((wn + g * 16 + l15) * 32 + l4 * 8) * 2);
#pragma unroll
    for (int f = 0; f < 4; ++f)
#pragma unroll
      for (int g = 0; g < 4; ++g)
        acc[f][g] = __builtin_amdgcn_mfma_f32_16x16x32_bf16(a[f], b[g], acc[f][g], 0, 0, 0);
  }
  const float alpha = __expf(log_alpha_p[0]);
#pragma unroll
  for (int g = 0; g < 4; ++g) {
    const int e = e0 + wn + g * 16 + l15;
    const float bv = bias[e];
#pragma unroll
    for (int f = 0; f < 4; ++f) {
#pragma unroll
      for (int r = 0; r < 4; ++r) {
        const int m = m0 + wm + f * 16 + l4 * 4 + r;
        hreg[(size_t)(m + BATCH) * DIM + e] = alpha * (acc[f][g][r] + bv);
      }
    }
  }
}

// ---------------- DPP wave-sum helper (total lands in lane 63) ----------------
__device__ __forceinline__ float dpp_sum_reg(float x) {
  float acc = x;
#define DPP_ADD(ctrl)                                                              \
  {                                                                                \
    int t_ = __builtin_amdgcn_update_dpp(0, __float_as_int(acc), (ctrl), 0xf, 0xf, \
                                         true);                                    \
    acc += __int_as_float(t_);                                                     \
  }
  DPP_ADD(0x111); DPP_ADD(0x112); DPP_ADD(0x114); DPP_ADD(0x118);
  DPP_ADD(0x142); DPP_ADD(0x143);
#undef DPP_ADD
  return acc;
}

// ---- precompute: scal4[t]=(e, 2d, 2d2, 2d3), d45[t]=(2d4, 2d5)  (dk = W_{t-k}.W_t)
// TILED (r15): one block computes 8 consecutive t for one batch row, holding the
// 13-row sliding window in registers.
__global__ __launch_bounds__(64, 1) void dots_kernel(const float* __restrict__ hreg,
                                                     float4* __restrict__ scal4,
                                                     float2* __restrict__ d45g) {
  const int tile = blockIdx.x >> 4;   // 256 tiles of 8 t-values
  const int b = blockIdx.x & 15;
  const int t0 = tile * 8;
  const int lane = threadIdx.x;
  const float4* h4 = (const float4*)hreg;

  float4 R[13][4];
#pragma unroll
  for (int k = 0; k < 13; ++k) {
    int si = t0 - 4 + k;            // slot index (W_{si-1} lives at slot si)
    if (si < 0) si = 0;             // tile 0 only; values discarded by guards
#pragma unroll
    for (int j = 0; j < 4; ++j)
      R[k][j] = h4[(size_t)si * SLOT4C + b * 256 + lane + 64 * j];
  }

#pragma unroll
  for (int u = 0; u < 8; ++u) {
    const int t = t0 + u;
    float e = 0.f, d = 0.f, d2 = 0.f, d3 = 0.f, d4 = 0.f, d5 = 0.f;
#pragma unroll
    for (int j = 0; j < 4; ++j) {
      const float4 a = R[u + 5][j];   // W_t       (slot t+1)
      e = fmaf(a.x, a.x, fmaf(a.y, a.y, fmaf(a.z, a.z, fmaf(a.w, a.w, e))));
      const float4 p1 = R[u + 4][j];  // W_{t-1}
      d = fmaf(p1.x, a.x, fmaf(p1.y, a.y, fmaf(p1.z, a.z, fmaf(p1.w, a.w, d))));
      const float4 p2 = R[u + 3][j];  // W_{t-2}
      d2 = fmaf(p2.x, a.x, fmaf(p2.y, a.y, fmaf(p2.z, a.z, fmaf(p2.w, a.w, d2))));
      const float4 p3 = R[u + 2][j];  // W_{t-3}
      d3 = fmaf(p3.x, a.x, fmaf(p3.y, a.y, fmaf(p3.z, a.z, fmaf(p3.w, a.w, d3))));
      const float4 p4 = R[u + 1][j];  // W_{t-4}
      d4 = fmaf(p4.x, a.x, fmaf(p4.y, a.y, fmaf(p4.z, a.z, fmaf(p4.w, a.w, d4))));
      const float4 p5 = R[u][j];      // W_{t-5}
      d5 = fmaf(p5.x, a.x, fmaf(p5.y, a.y, fmaf(p5.z, a.z, fmaf(p5.w, a.w, d5))));
    }
    e = dpp_sum_reg(e);
    d = dpp_sum_reg(d);
    d2 = dpp_sum_reg(d2);
    d3 = dpp_sum_reg(d3);
    d4 = dpp_sum_reg(d4);
    d5 = dpp_sum_reg(d5);
    if (lane == 63) {
      const float dd  = (t >= 1) ? d + d : 0.f;
      const float dd2 = (t >= 2) ? d2 + d2 : 0.f;
      const float dd3 = (t >= 3) ? d3 + d3 : 0.f;
      const float dd4 = (t >= 4) ? d4 + d4 : 0.f;
      const float dd5 = (t >= 5) ? d5 + d5 : 0.f;
      scal4[b * T_STEPS + t] = make_float4(e, dd, dd2, dd3);
      d45g[b * T_STEPS + t] = make_float2(dd4, dd5);
    }
  }
}

// ---------------- sequential scan, 4 waves/row, depth-5 pipeline (r7, 323us) -----
__global__ __launch_bounds__(256, 1) void scan_kernel(
    const float* __restrict__ h0,
    const float4* __restrict__ scal4,
    const float2* __restrict__ d45g,
    float* __restrict__ hreg) {
  const int b = blockIdx.x;
  const int tid = threadIdx.x;
  const int wave = tid >> 6;
  const int lane = tid & 63;
  float4* h4 = (float4*)hreg;
  const int idx4 = b * 256 + tid;

  __shared__ float4 scLDS[T_STEPS];          // 32 KB
  __shared__ float2 d45LDS[T_STEPS];         // 16 KB
  __shared__ alignas(16) float Gp[4][4];     // [target&3][wave]
  __shared__ float initP[4][6];

#pragma unroll
  for (int p = 0; p < 8; ++p)
    scLDS[p * 256 + tid] = scal4[b * T_STEPS + p * 256 + tid];
#pragma unroll
  for (int p = 0; p < 8; ++p)
    d45LDS[p * 256 + tid] = d45g[b * T_STEPS + p * 256 + tid];

  // W ring-16: w[k] = W_k for k=2..15, w[0]=W_16, w[1]=W_17  (W_j at hreg slot j+1)
  float4 w[16];
#pragma unroll
  for (int k = 2; k < 16; ++k) w[k] = h4[(size_t)SLOT4C * (k + 1) + idx4];
  w[0] = h4[(size_t)SLOT4C * 17 + idx4];
  w[1] = h4[(size_t)SLOT4C * 18 + idx4];
  float4 w0v = h4[(size_t)SLOT4C * 1 + idx4];  // W_0
  float4 w1v = h4[(size_t)SLOT4C * 2 + idx4];  // W_1
  float4 h0v = ((const float4*)h0)[idx4];
  h4[idx4] = h0v;  // slot 0 = h_0

  // startup direct reductions off s_1 = h_0 + W_0
  float4 s;
  s.x = h0v.x + w0v.x; s.y = h0v.y + w0v.y;
  s.z = h0v.z + w0v.z; s.w = h0v.w + w0v.w;
  {
    float q  = dpp_sum_reg(dot4(s, s));
    float r  = dpp_sum_reg(dot4(s, w1v));
    float c2 = dpp_sum_reg(dot4(s, w[2]));
    float c3 = dpp_sum_reg(dot4(s, w[3]));
    float c4 = dpp_sum_reg(dot4(s, w[4]));
    float c5 = dpp_sum_reg(dot4(s, w[5]));
    if (lane == 63) {
      initP[wave][0] = q;  initP[wave][1] = r;  initP[wave][2] = c2;
      initP[wave][3] = c3; initP[wave][4] = c4; initP[wave][5] = c5;
    }
  }
  __syncthreads();
  const float n1 = (initP[0][0] + initP[1][0]) + (initP[2][0] + initP[3][0]);
  float t1 = (initP[0][1] + initP[1][1]) + (initP[2][1] + initP[3][1]);
  float t2 = (initP[0][2] + initP[1][2]) + (initP[2][2] + initP[3][2]);
  float t3 = (initP[0][3] + initP[1][3]) + (initP[2][3] + initP[3][3]);
  float t4 = (initP[0][4] + initP[1][4]) + (initP[2][4] + initP[3][4]);
  float t5 = (initP[0][5] + initP[1][5]) + (initP[2][5] + initP[3][5]);
  const float B1 = t1 + t1, C2 = t2 + t2, C3 = t3 + t3, C4 = t4 + t4, C5 = t5 + t5;

  const float e1 = scLDS[1].x;
  float4 sc2 = scLDS[2], sc3 = scLDS[3], sc4 = scLDS[4], sc5 = scLDS[5];
  const float D45x = d45LDS[5].x;  // 2*d4_5
  float4 scA = scLDS[6], scB = scLDS[7];
  float2 d45A = d45LDS[6], d45B = d45LDS[7];

  float n = n1, rm1, rm2, rm3, rm4, pp;
  float gr0 = 0.f, gr1 = 0.f;
  float4 rv = make_float4(0.f, 0.f, 0.f, 0.f);
  float4 hvr[4];  // store-data register ring (static indices)

#define BAR0 { asm volatile("s_waitcnt lgkmcnt(0)" ::: "memory"); __builtin_amdgcn_s_barrier(); }

  // ---- step 1
  {
    const float rinv = fast_rsq(fmaf(n, INVD, EPSV));
    n = fmaf(rinv, fmaf(rinv, n, B1), e1);
    hvr[1].x = rinv * s.x; hvr[1].y = rinv * s.y;
    hvr[1].z = rinv * s.z; hvr[1].w = rinv * s.w;
    h4[(size_t)SLOT4C * 1 + idx4] = hvr[1];
    s.x = hvr[1].x + w1v.x; s.y = hvr[1].y + w1v.y;
    s.z = hvr[1].z + w1v.z; s.w = hvr[1].w + w1v.w;
    pp = dpp_sum_reg(dot4(hvr[1], w[6]));  // G_6 partial
    rm1 = rinv;
    BAR0
  }
  // ---- step 2
  {
    if (lane == 63) Gp[2][wave] = pp;  // target 6
    const float rinv = fast_rsq(fmaf(n, INVD, EPSV));
    const float BB = fmaf(rm1, C2, sc2.y);
    n = fmaf(rinv, fmaf(rinv, n, BB), sc2.x);
    hvr[2].x = rinv * s.x; hvr[2].y = rinv * s.y;
    hvr[2].z = rinv * s.z; hvr[2].w = rinv * s.w;
    h4[(size_t)SLOT4C * 2 + idx4] = hvr[2];
    s.x = hvr[2].x + w[2].x; s.y = hvr[2].y + w[2].y;
    s.z = hvr[2].z + w[2].z; s.w = hvr[2].w + w[2].w;
    pp = dpp_sum_reg(dot4(hvr[2], w[7]));  // G_7 partial
    w[2] = h4[(size_t)SLOT4C * 19 + idx4];  // W_18
    rm2 = rm1; rm1 = rinv;
    BAR0
  }
  // ---- step 3
  {
    if (lane == 63) Gp[3][wave] = pp;  // target 7
    const float rinv = fast_rsq(fmaf(n, INVD, EPSV));
    const float BB = fmaf(rm1, fmaf(rm2, C3, sc3.z), sc3.y);
    n = fmaf(rinv, fmaf(rinv, n, BB), sc3.x);
    hvr[3].x = rinv * s.x; hvr[3].y = rinv * s.y;
    hvr[3].z = rinv * s.z; hvr[3].w = rinv * s.w;
    h4[(size_t)SLOT4C * 3 + idx4] = hvr[3];
    s.x = hvr[3].x + w[3].x; s.y = hvr[3].y + w[3].y;
    s.z = hvr[3].z + w[3].z; s.w = hvr[3].w + w[3].w;
    pp = dpp_sum_reg(dot4(hvr[3], w[8]));  // G_8 partial
    w[3] = h4[(size_t)SLOT4C * 20 + idx4];  // W_19
    rm3 = rm2; rm2 = rm1; rm1 = rinv;
    BAR0
  }
  // ---- step 4
  {
    if (lane == 63) Gp[0][wave] = pp;  // target 8
    const float rinv = fast_rsq(fmaf(n, INVD, EPSV));
    const float BB = fmaf(rm1, fmaf(rm2, fmaf(rm3, C4, sc4.w), sc4.z), sc4.y);
    n = fmaf(rinv, fmaf(rinv, n, BB), sc4.x);
    rv = *(const float4*)&Gp[2][0];  // target-6 partials
    hvr[0].x = rinv * s.x; hvr[0].y = rinv * s.y;
    hvr[0].z = rinv * s.z; hvr[0].w = rinv * s.w;
    h4[(size_t)SLOT4C * 4 + idx4] = hvr[0];
    s.x = hvr[0].x + w[4].x; s.y = hvr[0].y + w[4].y;
    s.z = hvr[0].z + w[4].z; s.w = hvr[0].w + w[4].w;
    pp = dpp_sum_reg(dot4(hvr[0], w[9]));  // G_9 partial
    w[4] = h4[(size_t)SLOT4C * 21 + idx4];  // W_20
    rm4 = rm3; rm3 = rm2; rm2 = rm1; rm1 = rinv;
    BAR0
  }
  // ---- step 5
  {
    if (lane == 63) Gp[1][wave] = pp;  // target 9
    const float rinv = fast_rsq(fmaf(n, INVD, EPSV));
    const float BB =
        fmaf(rm1, fmaf(rm2, fmaf(rm3, fmaf(rm4, C5, D45x), sc5.w), sc5.z), sc5.y);
    n = fmaf(rinv, fmaf(rinv, n, BB), sc5.x);
    { float gt = (rv.x + rv.y) + (rv.z + rv.w); gr0 = gt + gt; }  // 2*G_6
    rv = *(const float4*)&Gp[3][0];  // target-7 partials
    hvr[1].x = rinv * s.x; hvr[1].y = rinv * s.y;
    hvr[1].z = rinv * s.z; hvr[1].w = rinv * s.w;
    h4[(size_t)SLOT4C * 5 + idx4] = hvr[1];
    s.x = hvr[1].x + w[5].x; s.y = hvr[1].y + w[5].y;
    s.z = hvr[1].z + w[5].z; s.w = hvr[1].w + w[5].w;
    pp = dpp_sum_reg(dot4(hvr[1], w[10]));  // G_10 partial
    w[5] = h4[(size_t)SLOT4C * 22 + idx4];  // W_21
    rm4 = rm3; rm3 = rm2; rm2 = rm1; rm1 = rinv;
    BAR0
  }

// Steady step i>=6 (r7 schedule).
#define STEP(I_, WS, W5S, GW, GR, SCR, D45R, GRU, GRW, HVI, BAR_)                    \
  {                                                                                  \
    const int i_ = (I_);                                                             \
    if (lane == 63) Gp[GW][wave] = pp;                                               \
    { float gt_ = (rv.x + rv.y) + (rv.z + rv.w); GRW = gt_ + gt_; }                  \
    rv = *(const float4*)&Gp[GR][0];                                                 \
    const float rinv = fast_rsq(fmaf(n, INVD, EPSV));                                \
    const float BB = fmaf(                                                           \
        rm1, fmaf(rm2, fmaf(rm3, fmaf(rm4, (D45R).y + (GRU), (D45R).x), (SCR).w),    \
                  (SCR).z), (SCR).y);                                                \
    n = fmaf(rinv, fmaf(rinv, n, BB), (SCR).x);                                      \
    hvr[HVI].x = rinv * s.x; hvr[HVI].y = rinv * s.y;                                \
    hvr[HVI].z = rinv * s.z; hvr[HVI].w = rinv * s.w;                                \
    h4[(size_t)SLOT4C * i_ + idx4] = hvr[HVI];                                       \
    s.x = hvr[HVI].x + w[WS].x; s.y = hvr[HVI].y + w[WS].y;                          \
    s.z = hvr[HVI].z + w[WS].z; s.w = hvr[HVI].w + w[WS].w;                          \
    pp = dpp_sum_reg(dot4(hvr[HVI], w[W5S]));                                        \
    const int ipf_ = (i_ + 16 < T_STEPS) ? (i_ + 16) : (T_STEPS - 1);                \
    w[WS] = h4[(size_t)SLOT4C * (ipf_ + 1) + idx4];                                  \
    const int isc_ = (i_ + 2 < T_STEPS) ? (i_ + 2) : (T_STEPS - 1);                  \
    SCR = scLDS[isc_];                                                               \
    D45R = d45LDS[isc_];                                                             \
    rm4 = rm3; rm3 = rm2; rm2 = rm1; rm1 = rinv;                                     \
    if (BAR_) { asm volatile("s_waitcnt lgkmcnt(3)" ::: "memory");                   \
                __builtin_amdgcn_s_barrier(); }                                      \
  }

  // main loop: i = 6..2037 in chunks of 16 (ii ≡ 6 mod 16); HVI = i&3
  for (int ii = 6; ii < 2038; ii += 16) {
    STEP(ii + 0,  6, 11, 2, 0, scA, d45A, gr0, gr1, 2, 0)
    STEP(ii + 1,  7, 12, 3, 1, scB, d45B, gr1, gr0, 3, 1)
    STEP(ii + 2,  8, 13, 0, 2, scA, d45A, gr0, gr1, 0, 0)
    STEP(ii + 3,  9, 14, 1, 3, scB, d45B, gr1, gr0, 1, 1)
    STEP(ii + 4, 10, 15, 2, 0, scA, d45A, gr0, gr1, 2, 0)
    STEP(ii + 5, 11,  0, 3, 1, scB, d45B, gr1, gr0, 3, 1)
    STEP(ii + 6, 12,  1, 0, 2, scA, d45A, gr0, gr1, 0, 0)
    STEP(ii + 7, 13,  2, 1, 3, scB, d45B, gr1, gr0, 1, 1)
    STEP(ii + 8, 14,  3, 2, 0, scA, d45A, gr0, gr1, 2, 0)
    STEP(ii + 9, 15,  4, 3, 1, scB, d45B, gr1, gr0, 3, 1)
    STEP(ii + 10, 0,  5, 0, 2, scA, d45A, gr0, gr1, 0, 0)
    STEP(ii + 11, 1,  6, 1, 3, scB, d45B, gr1, gr0, 1, 1)
    STEP(ii + 12, 2,  7, 2, 0, scA, d45A, gr0, gr1, 2, 0)
    STEP(ii + 13, 3,  8, 3, 1, scB, d45B, gr1, gr0, 3, 1)
    STEP(ii + 14, 4,  9, 0, 2, scA, d45A, gr0, gr1, 0, 0)
    STEP(ii + 15, 5, 10, 1, 3, scB, d45B, gr1, gr0, 1, 1)
  }
  // tail: i = 2038..2047 (continues pattern, 2038 ≡ 6 mod 16)
  STEP(2038,  6, 11, 2, 0, scA, d45A, gr0, gr1, 2, 0)
  STEP(2039,  7, 12, 3, 1, scB, d45B, gr1, gr0, 3, 1)
  STEP(2040,  8, 13, 0, 2, scA, d45A, gr0, gr1, 0, 0)
  STEP(2041,  9, 14, 1, 3, scB, d45B, gr1, gr0, 1, 1)
  STEP(2042, 10, 15, 2, 0, scA, d45A, gr0, gr1, 2, 0)
  STEP(2043, 11,  0, 3, 1, scB, d45B, gr1, gr0, 3, 1)
  STEP(2044, 12,  1, 0, 2, scA, d45A, gr0, gr1, 0, 0)
  STEP(2045, 13,  2, 1, 3, scB, d45B, gr1, gr0, 1, 1)
  STEP(2046, 14,  3, 2, 0, scA, d45A, gr0, gr1, 2, 0)
  STEP(2047, 15,  4, 3, 1, scB, d45B, gr1, gr0, 3, 1)
#undef STEP
#undef BAR0

  // final: h_2048 = rinv * s -> slot 2048
  const float rinvT = fast_rsq(fmaf(n, INVD, EPSV));
  float4 o;
  o.x = rinvT * s.x; o.y = rinvT * s.y; o.z = rinvT * s.z; o.w = rinvT * s.w;
  h4[(size_t)SLOT4C * T_STEPS + idx4] = o;
}

// ---------------- outs[t] = h_{t+1} * silu(h_{t+1}) (grid-stride, 2048 blocks) ----
__global__ __launch_bounds__(256) void silu_kernel(const float4* __restrict__ hsrc,
                                                   float4* __restrict__ out4, int n4) {
  for (int i = blockIdx.x * 256 + threadIdx.x; i < n4; i += 2048 * 256) {
    float4 h = hsrc[i];
    float4 o;
    o.x = h.x * h.x / (1.f + __expf(-h.x));
    o.y = h.y * h.y / (1.f + __expf(-h.y));
    o.z = h.z * h.z / (1.f + __expf(-h.z));
    o.w = h.w * h.w / (1.f + __expf(-h.w));
    out4[i] = o;
  }
}

extern "C" void kernel_launch(void* const* d_in, const int* in_sizes, int n_in,
                              void* d_out, int out_size, void* d_ws, size_t ws_size,
                              hipStream_t stream) {
  (void)in_sizes; (void)n_in; (void)d_ws; (void)ws_size; (void)out_size;
  const float* x = (const float*)d_in[0];
  const float* h0 = (const float*)d_in[1];
  const float* W = (const float*)d_in[2];
  const float* bias = (const float*)d_in[3];
  const float* log_alpha = (const float*)d_in[4];

  float* out = (float*)d_out;                               // outs region [T][B][D]
  float* hreg = out + (size_t)T_STEPS * BATCH * DIM;        // h region [T+1][B][D]
  // staging overlays the outs region (consumed before scan/silu touch it)
  __hip_bfloat16* xb = (__hip_bfloat16*)d_out;
  __hip_bfloat16* wb = (__hip_bfloat16*)((char*)d_out + (size_t)T_STEPS * BATCH * DIM * 2);
  float4* scal4 = (float4*)(out + (size_t)26 * 1024 * 1024);  // 104 MB offset
  float2* d45g = (float2*)(out + (size_t)27 * 1024 * 1024);   // 108 MB offset

  const int nx8 = T_STEPS * BATCH * DIM / 8;   // 4,194,304
  const int nw8 = DIM * DIM / 8;               // 131,072
  const int ntot8 = nx8 + nw8;
  cvt_kernel<<<(ntot8 + 255) / 256, 256, 0, stream>>>(x, W, (bf16x8pack*)xb,
                                                      (bf16x8pack*)wb, nx8, ntot8);

  gemm_kernel<<<2048, 256, 0, stream>>>(xb, wb, bias, log_alpha, hreg);

  dots_kernel<<<(T_STEPS / 8) * BATCH, 64, 0, stream>>>(hreg, scal4, d45g);

  scan_kernel<<<BATCH, 256, 0, stream>>>(h0, scal4, d45g, hreg);

  const int n4 = T_STEPS * BATCH * DIM / 4;
  silu_kernel<<<2048, 256, 0, stream>>>((const float4*)(hreg + BATCH * DIM),
                                        (float4*)out, n4);
}

// Round 17
// 503.732 us; speedup vs baseline: 1.4021x; 1.0158x over previous
//
#include <hip/hip_runtime.h>
#include <hip/hip_bf16.h>

#define T_STEPS 2048
#define BATCH 16
#define DIM 1024
#define EPSV 1e-6f
#define INVD (1.0f / 1024.0f)
#define SLOTF (BATCH * DIM)      // floats per [B][D] slot
#define SLOT4C (BATCH * DIM / 4) // float4 per slot

typedef short short8 __attribute__((ext_vector_type(8)));
typedef float f32x4 __attribute__((ext_vector_type(4)));

struct alignas(16) bf16x8pack { __hip_bfloat16 v[8]; };

__device__ __forceinline__ float dot4(const float4& a, const float4& c) {
  return fmaf(a.x, c.x, fmaf(a.y, c.y, fmaf(a.z, c.z, a.w * c.w)));
}
__device__ __forceinline__ float fast_rsq(float x) {
  float r;
  asm("v_rsq_f32 %0, %1" : "=v"(r) : "v"(x));
  return r;
}

// ---------------- fused fp32 -> bf16 convert (x then W, one launch) ----------------
__global__ __launch_bounds__(256) void cvt_kernel(const float* __restrict__ xsrc,
                                                  const float* __restrict__ wsrc,
                                                  bf16x8pack* __restrict__ xdst,
                                                  bf16x8pack* __restrict__ wdst,
                                                  int nx8, int ntot8) {
  int i = blockIdx.x * blockDim.x + threadIdx.x;
  if (i >= ntot8) return;
  const float* src;
  bf16x8pack* dst;
  int k;
  if (i < nx8) { src = xsrc; dst = xdst; k = i; }
  else         { src = wsrc; dst = wdst; k = i - nx8; }
  const float4* s4 = (const float4*)src + (size_t)k * 2;
  float4 a = s4[0];
  float4 b = s4[1];
  bf16x8pack p;
  p.v[0] = __float2bfloat16(a.x); p.v[1] = __float2bfloat16(a.y);
  p.v[2] = __float2bfloat16(a.z); p.v[3] = __float2bfloat16(a.w);
  p.v[4] = __float2bfloat16(b.x); p.v[5] = __float2bfloat16(b.y);
  p.v[6] = __float2bfloat16(b.z); p.v[7] = __float2bfloat16(b.w);
  dst[k] = p;
}

// ---------------- 256x256 deep-pipelined bf16 MFMA GEMM -------------------------
// out[m][e] = alpha*(sum_d X[m][d]*W[e][d] + b[e]).
// r17 structure (T2+T3/T4+T5 derivation, fully race-analyzed):
//  * BK=32 K-tiles in a 4-slot LDS ring (4 x (A 16KB + B 16KB) = 128 KB).
//  * Staging runs TWO tiles ahead via global_load_lds (4 loads/tile: A j0,j1 in
//    phase 1, B j0,j1 in phase 2). vmcnt(4) at each tile's phase-1 top confirms
//    tile k's loads (leaves tile k+1's 4 in flight -> never drains).
//  * Slot-overwrite safety: stage of tile k+2 overwrites tile k-2's slot, whose
//    last ds_read completed before a lgkmcnt(0) >=4 barriers earlier.
//  * T2 swizzle: byte ^= ((row&3)<<4) on [256 rows][64B] tiles (involution;
//    applied as pre-swizzled global source + swizzled ds_read; gives uniform
//    8 lanes per 16B bank-slot = optimal for wave64 ds_read_b128).
//  * 8 waves (2 M x 4 N), per-wave 128x64 output, acc[8][4] f32x4.
//  * T5 setprio around each 16-MFMA cluster; XCD-chunked block swizzle.
__global__ __launch_bounds__(512, 1) void gemm_kernel(
    const __hip_bfloat16* __restrict__ Xb,
    const __hip_bfloat16* __restrict__ Wb,
    const float* __restrict__ bias,
    const float* __restrict__ log_alpha_p,
    float* __restrict__ hreg) {
  __shared__ char lds[4 * 32768];
  const int tid = threadIdx.x;
  const int w = tid >> 6, l = tid & 63;
  const int d = blockIdx.x;
  const int work = ((d & 7) << 6) + (d >> 3);   // bijective on [0,512)
  const int mt = work >> 2;                     // 0..127  (M tile)
  const int et = work & 3;                      // 0..3    (N tile)
  const int wr = w >> 2, wc = w & 3;
  const int l15 = l & 15, l4 = l >> 4;

  f32x4 acc[8][4] = {};

  // staging lane decomposition: 4 lanes/row, pre-swizzled source k-offset
  const int srow = w * 16 + (l >> 2);                 // row within 128-row issue
  const int scol = 8 * ((l & 3) ^ ((l >> 2) & 3));    // k elems (inverse-swz)
  // read-side swizzled k-byte within the 64B row
  const int kxor = (l4 * 16) ^ ((l & 3) << 4);

  const __hip_bfloat16* Abase = Xb + (size_t)(mt * 256 + srow) * DIM + scol;
  const __hip_bfloat16* Bbase = Wb + (size_t)(et * 256 + srow) * DIM + scol;

#define GLD1(GSRC, LOFF)                                                           \
  __builtin_amdgcn_global_load_lds(                                                \
      (const __attribute__((address_space(1))) void*)(GSRC),                       \
      (__attribute__((address_space(3))) void*)(lds + (LOFF)), 16, 0, 0)
#define STAGE_A(SLOT, KT)                                                          \
  GLD1(Abase + (KT), (SLOT) * 32768 + w * 1024);                                   \
  GLD1(Abase + (KT) + 128 * DIM, (SLOT) * 32768 + 8192 + w * 1024);
#define STAGE_B(SLOT, KT)                                                          \
  GLD1(Bbase + (KT), (SLOT) * 32768 + 16384 + w * 1024);                           \
  GLD1(Bbase + (KT) + 128 * DIM, (SLOT) * 32768 + 16384 + 8192 + w * 1024);

  // ---- prologue: stage tiles 0 (slot 0) and 1 (slot 1); drain; barrier
  STAGE_A(0, 0) STAGE_B(0, 0)
  STAGE_A(1, 32) STAGE_B(1, 32)
  asm volatile("s_waitcnt vmcnt(0)" ::: "memory");
  __builtin_amdgcn_s_barrier();

  short8 a_[4], b_[4];

// Phase 1 of tile (slot SL): read A f0-3 + B g0-3; stage A of tile+2; MFMA f0-3.
#define PH1(SL, STSL, STKT, DOST)                                                  \
  {                                                                                \
    asm volatile("s_waitcnt vmcnt(4)" ::: "memory");                               \
    __builtin_amdgcn_sched_barrier(0);                                             \
    const char* As_ = lds + (SL) * 32768;                                          \
    const char* Bs_ = As_ + 16384;                                                 \
    _Pragma("unroll")                                                              \
    for (int f = 0; f < 4; ++f)                                                    \
      a_[f] = *(const short8*)(As_ + (wr * 128 + f * 16 + l15) * 64 + kxor);       \
    _Pragma("unroll")                                                              \
    for (int g = 0; g < 4; ++g)                                                    \
      b_[g] = *(const short8*)(Bs_ + (wc * 64 + g * 16 + l15) * 64 + kxor);        \
    if (DOST) { STAGE_A(STSL, STKT) }                                              \
    __builtin_amdgcn_s_barrier();                                                  \
    asm volatile("s_waitcnt lgkmcnt(0)" ::: "memory");                             \
    __builtin_amdgcn_sched_barrier(0);                                             \
    __builtin_amdgcn_s_setprio(1);                                                 \
    _Pragma("unroll")                                                              \
    for (int f = 0; f < 4; ++f)                                                    \
      _Pragma("unroll")                                                            \
      for (int g = 0; g < 4; ++g)                                                  \
        acc[f][g] = __builtin_amdgcn_mfma_f32_16x16x32_bf16(a_[f], b_[g],          \
                                                            acc[f][g], 0, 0, 0);  \
    __builtin_amdgcn_s_setprio(0);                                                 \
    __builtin_amdgcn_s_barrier();                                                  \
  }
// Phase 2: read A f4-7 (B g0-3 still live); stage B of tile+2; MFMA f4-7.
#define PH2(SL, STSL, STKT, DOST)                                                  \
  {                                                                                \
    const char* As_ = lds + (SL) * 32768;                                          \
    _Pragma("unroll")                                                              \
    for (int f = 0; f < 4; ++f)                                                    \
      a_[f] = *(const short8*)(As_ + (wr * 128 + (f + 4) * 16 + l15) * 64 + kxor); \
    if (DOST) { STAGE_B(STSL, STKT) }                                              \
    __builtin_amdgcn_s_barrier();                                                  \
    asm volatile("s_waitcnt lgkmcnt(0)" ::: "memory");                             \
    __builtin_amdgcn_sched_barrier(0);                                             \
    __builtin_amdgcn_s_setprio(1);                                                 \
    _Pragma("unroll")                                                              \
    for (int f = 0; f < 4; ++f)                                                    \
      _Pragma("unroll")                                                            \
      for (int g = 0; g < 4; ++g)                                                  \
        acc[f + 4][g] = __builtin_amdgcn_mfma_f32_16x16x32_bf16(a_[f], b_[g],      \
                                                                acc[f + 4][g],    \
                                                                0, 0, 0);         \
    __builtin_amdgcn_s_setprio(0);                                                 \
    __builtin_amdgcn_s_barrier();                                                  \
  }

  // ---- main loop: tiles 0..29 (stage tile k+2), then 30,31 without staging
  for (int k = 0; k < 30; ++k) {
    const int sl = k & 3;
    const int st = (k + 2) & 3;
    const int stkt = (k + 2) * 32;
    PH1(sl, st, stkt, 1)
    PH2(sl, st, stkt, 1)
  }
  PH1(2, 0, 0, 0) PH2(2, 0, 0, 0)   // tile 30
  PH1(3, 0, 0, 0) PH2(3, 0, 0, 0)   // tile 31
#undef PH1
#undef PH2
#undef STAGE_A
#undef STAGE_B
#undef GLD1

  // ---- epilogue: C = alpha*(acc + bias)  (D map: col=l&15, row=(l>>4)*4+r)
  const float alpha = __expf(log_alpha_p[0]);
#pragma unroll
  for (int g = 0; g < 4; ++g) {
    const int e = et * 256 + wc * 64 + g * 16 + l15;
    const float bv = bias[e];
#pragma unroll
    for (int f = 0; f < 8; ++f) {
#pragma unroll
      for (int r = 0; r < 4; ++r) {
        const int m = mt * 256 + wr * 128 + f * 16 + l4 * 4 + r;
        hreg[(size_t)(m + BATCH) * DIM + e] = alpha * (acc[f][g][r] + bv);
      }
    }
  }
}

// ---------------- DPP wave-sum helper (total lands in lane 63) ----------------
__device__ __forceinline__ float dpp_sum_reg(float x) {
  float acc = x;
#define DPP_ADD(ctrl)                                                              \
  {                                                                                \
    int t_ = __builtin_amdgcn_update_dpp(0, __float_as_int(acc), (ctrl), 0xf, 0xf, \
                                         true);                                    \
    acc += __int_as_float(t_);                                                     \
  }
  DPP_ADD(0x111); DPP_ADD(0x112); DPP_ADD(0x114); DPP_ADD(0x118);
  DPP_ADD(0x142); DPP_ADD(0x143);
#undef DPP_ADD
  return acc;
}

// ---- precompute: scal4[t]=(e, 2d, 2d2, 2d3), d45[t]=(2d4, 2d5)  (dk = W_{t-k}.W_t)
// TILED (r15): one block computes 8 consecutive t for one batch row.
__global__ __launch_bounds__(64, 1) void dots_kernel(const float* __restrict__ hreg,
                                                     float4* __restrict__ scal4,
                                                     float2* __restrict__ d45g) {
  const int tile = blockIdx.x >> 4;
  const int b = blockIdx.x & 15;
  const int t0 = tile * 8;
  const int lane = threadIdx.x;
  const float4* h4 = (const float4*)hreg;

  float4 R[13][4];
#pragma unroll
  for (int k = 0; k < 13; ++k) {
    int si = t0 - 4 + k;
    if (si < 0) si = 0;
#pragma unroll
    for (int j = 0; j < 4; ++j)
      R[k][j] = h4[(size_t)si * SLOT4C + b * 256 + lane + 64 * j];
  }

#pragma unroll
  for (int u = 0; u < 8; ++u) {
    const int t = t0 + u;
    float e = 0.f, d = 0.f, d2 = 0.f, d3 = 0.f, d4 = 0.f, d5 = 0.f;
#pragma unroll
    for (int j = 0; j < 4; ++j) {
      const float4 a = R[u + 5][j];
      e = fmaf(a.x, a.x, fmaf(a.y, a.y, fmaf(a.z, a.z, fmaf(a.w, a.w, e))));
      const float4 p1 = R[u + 4][j];
      d = fmaf(p1.x, a.x, fmaf(p1.y, a.y, fmaf(p1.z, a.z, fmaf(p1.w, a.w, d))));
      const float4 p2 = R[u + 3][j];
      d2 = fmaf(p2.x, a.x, fmaf(p2.y, a.y, fmaf(p2.z, a.z, fmaf(p2.w, a.w, d2))));
      const float4 p3 = R[u + 2][j];
      d3 = fmaf(p3.x, a.x, fmaf(p3.y, a.y, fmaf(p3.z, a.z, fmaf(p3.w, a.w, d3))));
      const float4 p4 = R[u + 1][j];
      d4 = fmaf(p4.x, a.x, fmaf(p4.y, a.y, fmaf(p4.z, a.z, fmaf(p4.w, a.w, d4))));
      const float4 p5 = R[u][j];
      d5 = fmaf(p5.x, a.x, fmaf(p5.y, a.y, fmaf(p5.z, a.z, fmaf(p5.w, a.w, d5))));
    }
    e = dpp_sum_reg(e);
    d = dpp_sum_reg(d);
    d2 = dpp_sum_reg(d2);
    d3 = dpp_sum_reg(d3);
    d4 = dpp_sum_reg(d4);
    d5 = dpp_sum_reg(d5);
    if (lane == 63) {
      const float dd  = (t >= 1) ? d + d : 0.f;
      const float dd2 = (t >= 2) ? d2 + d2 : 0.f;
      const float dd3 = (t >= 3) ? d3 + d3 : 0.f;
      const float dd4 = (t >= 4) ? d4 + d4 : 0.f;
      const float dd5 = (t >= 5) ? d5 + d5 : 0.f;
      scal4[b * T_STEPS + t] = make_float4(e, dd, dd2, dd3);
      d45g[b * T_STEPS + t] = make_float2(dd4, dd5);
    }
  }
}

// ---------------- sequential scan, 4 waves/row, depth-5 pipeline (r7, 323us) -----
__global__ __launch_bounds__(256, 1) void scan_kernel(
    const float* __restrict__ h0,
    const float4* __restrict__ scal4,
    const float2* __restrict__ d45g,
    float* __restrict__ hreg) {
  const int b = blockIdx.x;
  const int tid = threadIdx.x;
  const int wave = tid >> 6;
  const int lane = tid & 63;
  float4* h4 = (float4*)hreg;
  const int idx4 = b * 256 + tid;

  __shared__ float4 scLDS[T_STEPS];
  __shared__ float2 d45LDS[T_STEPS];
  __shared__ alignas(16) float Gp[4][4];
  __shared__ float initP[4][6];

#pragma unroll
  for (int p = 0; p < 8; ++p)
    scLDS[p * 256 + tid] = scal4[b * T_STEPS + p * 256 + tid];
#pragma unroll
  for (int p = 0; p < 8; ++p)
    d45LDS[p * 256 + tid] = d45g[b * T_STEPS + p * 256 + tid];

  float4 w[16];
#pragma unroll
  for (int k = 2; k < 16; ++k) w[k] = h4[(size_t)SLOT4C * (k + 1) + idx4];
  w[0] = h4[(size_t)SLOT4C * 17 + idx4];
  w[1] = h4[(size_t)SLOT4C * 18 + idx4];
  float4 w0v = h4[(size_t)SLOT4C * 1 + idx4];
  float4 w1v = h4[(size_t)SLOT4C * 2 + idx4];
  float4 h0v = ((const float4*)h0)[idx4];
  h4[idx4] = h0v;

  float4 s;
  s.x = h0v.x + w0v.x; s.y = h0v.y + w0v.y;
  s.z = h0v.z + w0v.z; s.w = h0v.w + w0v.w;
  {
    float q  = dpp_sum_reg(dot4(s, s));
    float r  = dpp_sum_reg(dot4(s, w1v));
    float c2 = dpp_sum_reg(dot4(s, w[2]));
    float c3 = dpp_sum_reg(dot4(s, w[3]));
    float c4 = dpp_sum_reg(dot4(s, w[4]));
    float c5 = dpp_sum_reg(dot4(s, w[5]));
    if (lane == 63) {
      initP[wave][0] = q;  initP[wave][1] = r;  initP[wave][2] = c2;
      initP[wave][3] = c3; initP[wave][4] = c4; initP[wave][5] = c5;
    }
  }
  __syncthreads();
  const float n1 = (initP[0][0] + initP[1][0]) + (initP[2][0] + initP[3][0]);
  float t1 = (initP[0][1] + initP[1][1]) + (initP[2][1] + initP[3][1]);
  float t2 = (initP[0][2] + initP[1][2]) + (initP[2][2] + initP[3][2]);
  float t3 = (initP[0][3] + initP[1][3]) + (initP[2][3] + initP[3][3]);
  float t4 = (initP[0][4] + initP[1][4]) + (initP[2][4] + initP[3][4]);
  float t5 = (initP[0][5] + initP[1][5]) + (initP[2][5] + initP[3][5]);
  const float B1 = t1 + t1, C2 = t2 + t2, C3 = t3 + t3, C4 = t4 + t4, C5 = t5 + t5;

  const float e1 = scLDS[1].x;
  float4 sc2 = scLDS[2], sc3 = scLDS[3], sc4 = scLDS[4], sc5 = scLDS[5];
  const float D45x = d45LDS[5].x;
  float4 scA = scLDS[6], scB = scLDS[7];
  float2 d45A = d45LDS[6], d45B = d45LDS[7];

  float n = n1, rm1, rm2, rm3, rm4, pp;
  float gr0 = 0.f, gr1 = 0.f;
  float4 rv = make_float4(0.f, 0.f, 0.f, 0.f);
  float4 hvr[4];

#define BAR0 { asm volatile("s_waitcnt lgkmcnt(0)" ::: "memory"); __builtin_amdgcn_s_barrier(); }

  {  // step 1
    const float rinv = fast_rsq(fmaf(n, INVD, EPSV));
    n = fmaf(rinv, fmaf(rinv, n, B1), e1);
    hvr[1].x = rinv * s.x; hvr[1].y = rinv * s.y;
    hvr[1].z = rinv * s.z; hvr[1].w = rinv * s.w;
    h4[(size_t)SLOT4C * 1 + idx4] = hvr[1];
    s.x = hvr[1].x + w1v.x; s.y = hvr[1].y + w1v.y;
    s.z = hvr[1].z + w1v.z; s.w = hvr[1].w + w1v.w;
    pp = dpp_sum_reg(dot4(hvr[1], w[6]));
    rm1 = rinv;
    BAR0
  }
  {  // step 2
    if (lane == 63) Gp[2][wave] = pp;
    const float rinv = fast_rsq(fmaf(n, INVD, EPSV));
    const float BB = fmaf(rm1, C2, sc2.y);
    n = fmaf(rinv, fmaf(rinv, n, BB), sc2.x);
    hvr[2].x = rinv * s.x; hvr[2].y = rinv * s.y;
    hvr[2].z = rinv * s.z; hvr[2].w = rinv * s.w;
    h4[(size_t)SLOT4C * 2 + idx4] = hvr[2];
    s.x = hvr[2].x + w[2].x; s.y = hvr[2].y + w[2].y;
    s.z = hvr[2].z + w[2].z; s.w = hvr[2].w + w[2].w;
    pp = dpp_sum_reg(dot4(hvr[2], w[7]));
    w[2] = h4[(size_t)SLOT4C * 19 + idx4];
    rm2 = rm1; rm1 = rinv;
    BAR0
  }
  {  // step 3
    if (lane == 63) Gp[3][wave] = pp;
    const float rinv = fast_rsq(fmaf(n, INVD, EPSV));
    const float BB = fmaf(rm1, fmaf(rm2, C3, sc3.z), sc3.y);
    n = fmaf(rinv, fmaf(rinv, n, BB), sc3.x);
    hvr[3].x = rinv * s.x; hvr[3].y = rinv * s.y;
    hvr[3].z = rinv * s.z; hvr[3].w = rinv * s.w;
    h4[(size_t)SLOT4C * 3 + idx4] = hvr[3];
    s.x = hvr[3].x + w[3].x; s.y = hvr[3].y + w[3].y;
    s.z = hvr[3].z + w[3].z; s.w = hvr[3].w + w[3].w;
    pp = dpp_sum_reg(dot4(hvr[3], w[8]));
    w[3] = h4[(size_t)SLOT4C * 20 + idx4];
    rm3 = rm2; rm2 = rm1; rm1 = rinv;
    BAR0
  }
  {  // step 4
    if (lane == 63) Gp[0][wave] = pp;
    const float rinv = fast_rsq(fmaf(n, INVD, EPSV));
    const float BB = fmaf(rm1, fmaf(rm2, fmaf(rm3, C4, sc4.w), sc4.z), sc4.y);
    n = fmaf(rinv, fmaf(rinv, n, BB), sc4.x);
    rv = *(const float4*)&Gp[2][0];
    hvr[0].x = rinv * s.x; hvr[0].y = rinv * s.y;
    hvr[0].z = rinv * s.z; hvr[0].w = rinv * s.w;
    h4[(size_t)SLOT4C * 4 + idx4] = hvr[0];
    s.x = hvr[0].x + w[4].x; s.y = hvr[0].y + w[4].y;
    s.z = hvr[0].z + w[4].z; s.w = hvr[0].w + w[4].w;
    pp = dpp_sum_reg(dot4(hvr[0], w[9]));
    w[4] = h4[(size_t)SLOT4C * 21 + idx4];
    rm4 = rm3; rm3 = rm2; rm2 = rm1; rm1 = rinv;
    BAR0
  }
  {  // step 5
    if (lane == 63) Gp[1][wave] = pp;
    const float rinv = fast_rsq(fmaf(n, INVD, EPSV));
    const float BB =
        fmaf(rm1, fmaf(rm2, fmaf(rm3, fmaf(rm4, C5, D45x), sc5.w), sc5.z), sc5.y);
    n = fmaf(rinv, fmaf(rinv, n, BB), sc5.x);
    { float gt = (rv.x + rv.y) + (rv.z + rv.w); gr0 = gt + gt; }
    rv = *(const float4*)&Gp[3][0];
    hvr[1].x = rinv * s.x; hvr[1].y = rinv * s.y;
    hvr[1].z = rinv * s.z; hvr[1].w = rinv * s.w;
    h4[(size_t)SLOT4C * 5 + idx4] = hvr[1];
    s.x = hvr[1].x + w[5].x; s.y = hvr[1].y + w[5].y;
    s.z = hvr[1].z + w[5].z; s.w = hvr[1].w + w[5].w;
    pp = dpp_sum_reg(dot4(hvr[1], w[10]));
    w[5] = h4[(size_t)SLOT4C * 22 + idx4];
    rm4 = rm3; rm3 = rm2; rm2 = rm1; rm1 = rinv;
    BAR0
  }

#define STEP(I_, WS, W5S, GW, GR, SCR, D45R, GRU, GRW, HVI, BAR_)                    \
  {                                                                                  \
    const int i_ = (I_);                                                             \
    if (lane == 63) Gp[GW][wave] = pp;                                               \
    { float gt_ = (rv.x + rv.y) + (rv.z + rv.w); GRW = gt_ + gt_; }                  \
    rv = *(const float4*)&Gp[GR][0];                                                 \
    const float rinv = fast_rsq(fmaf(n, INVD, EPSV));                                \
    const float BB = fmaf(                                                           \
        rm1, fmaf(rm2, fmaf(rm3, fmaf(rm4, (D45R).y + (GRU), (D45R).x), (SCR).w),    \
                  (SCR).z), (SCR).y);                                                \
    n = fmaf(rinv, fmaf(rinv, n, BB), (SCR).x);                                      \
    hvr[HVI].x = rinv * s.x; hvr[HVI].y = rinv * s.y;                                \
    hvr[HVI].z = rinv * s.z; hvr[HVI].w = rinv * s.w;                                \
    h4[(size_t)SLOT4C * i_ + idx4] = hvr[HVI];                                       \
    s.x = hvr[HVI].x + w[WS].x; s.y = hvr[HVI].y + w[WS].y;                          \
    s.z = hvr[HVI].z + w[WS].z; s.w = hvr[HVI].w + w[WS].w;                          \
    pp = dpp_sum_reg(dot4(hvr[HVI], w[W5S]));                                        \
    const int ipf_ = (i_ + 16 < T_STEPS) ? (i_ + 16) : (T_STEPS - 1);                \
    w[WS] = h4[(size_t)SLOT4C * (ipf_ + 1) + idx4];                                  \
    const int isc_ = (i_ + 2 < T_STEPS) ? (i_ + 2) : (T_STEPS - 1);                  \
    SCR = scLDS[isc_];                                                               \
    D45R = d45LDS[isc_];                                                             \
    rm4 = rm3; rm3 = rm2; rm2 = rm1; rm1 = rinv;                                     \
    if (BAR_) { asm volatile("s_waitcnt lgkmcnt(3)" ::: "memory");                   \
                __builtin_amdgcn_s_barrier(); }                                      \
  }

  for (int ii = 6; ii < 2038; ii += 16) {
    STEP(ii + 0,  6, 11, 2, 0, scA, d45A, gr0, gr1, 2, 0)
    STEP(ii + 1,  7, 12, 3, 1, scB, d45B, gr1, gr0, 3, 1)
    STEP(ii + 2,  8, 13, 0, 2, scA, d45A, gr0, gr1, 0, 0)
    STEP(ii + 3,  9, 14, 1, 3, scB, d45B, gr1, gr0, 1, 1)
    STEP(ii + 4, 10, 15, 2, 0, scA, d45A, gr0, gr1, 2, 0)
    STEP(ii + 5, 11,  0, 3, 1, scB, d45B, gr1, gr0, 3, 1)
    STEP(ii + 6, 12,  1, 0, 2, scA, d45A, gr0, gr1, 0, 0)
    STEP(ii + 7, 13,  2, 1, 3, scB, d45B, gr1, gr0, 1, 1)
    STEP(ii + 8, 14,  3, 2, 0, scA, d45A, gr0, gr1, 2, 0)
    STEP(ii + 9, 15,  4, 3, 1, scB, d45B, gr1, gr0, 3, 1)
    STEP(ii + 10, 0,  5, 0, 2, scA, d45A, gr0, gr1, 0, 0)
    STEP(ii + 11, 1,  6, 1, 3, scB, d45B, gr1, gr0, 1, 1)
    STEP(ii + 12, 2,  7, 2, 0, scA, d45A, gr0, gr1, 2, 0)
    STEP(ii + 13, 3,  8, 3, 1, scB, d45B, gr1, gr0, 3, 1)
    STEP(ii + 14, 4,  9, 0, 2, scA, d45A, gr0, gr1, 0, 0)
    STEP(ii + 15, 5, 10, 1, 3, scB, d45B, gr1, gr0, 1, 1)
  }
  STEP(2038,  6, 11, 2, 0, scA, d45A, gr0, gr1, 2, 0)
  STEP(2039,  7, 12, 3, 1, scB, d45B, gr1, gr0, 3, 1)
  STEP(2040,  8, 13, 0, 2, scA, d45A, gr0, gr1, 0, 0)
  STEP(2041,  9, 14, 1, 3, scB, d45B, gr1, gr0, 1, 1)
  STEP(2042, 10, 15, 2, 0, scA, d45A, gr0, gr1, 2, 0)
  STEP(2043, 11,  0, 3, 1, scB, d45B, gr1, gr0, 3, 1)
  STEP(2044, 12,  1, 0, 2, scA, d45A, gr0, gr1, 0, 0)
  STEP(2045, 13,  2, 1, 3, scB, d45B, gr1, gr0, 1, 1)
  STEP(2046, 14,  3, 2, 0, scA, d45A, gr0, gr1, 2, 0)
  STEP(2047, 15,  4, 3, 1, scB, d45B, gr1, gr0, 3, 1)
#undef STEP
#undef BAR0

  const float rinvT = fast_rsq(fmaf(n, INVD, EPSV));
  float4 o;
  o.x = rinvT * s.x; o.y = rinvT * s.y; o.z = rinvT * s.z; o.w = rinvT * s.w;
  h4[(size_t)SLOT4C * T_STEPS + idx4] = o;
}

// ---------------- outs[t] = h_{t+1} * silu(h_{t+1}) (grid-stride, 2048 blocks) ----
__global__ __launch_bounds__(256) void silu_kernel(const float4* __restrict__ hsrc,
                                                   float4* __restrict__ out4, int n4) {
  for (int i = blockIdx.x * 256 + threadIdx.x; i < n4; i += 2048 * 256) {
    float4 h = hsrc[i];
    float4 o;
    o.x = h.x * h.x / (1.f + __expf(-h.x));
    o.y = h.y * h.y / (1.f + __expf(-h.y));
    o.z = h.z * h.z / (1.f + __expf(-h.z));
    o.w = h.w * h.w / (1.f + __expf(-h.w));
    out4[i] = o;
  }
}

extern "C" void kernel_launch(void* const* d_in, const int* in_sizes, int n_in,
                              void* d_out, int out_size, void* d_ws, size_t ws_size,
                              hipStream_t stream) {
  (void)in_sizes; (void)n_in; (void)d_ws; (void)ws_size; (void)out_size;
  const float* x = (const float*)d_in[0];
  const float* h0 = (const float*)d_in[1];
  const float* W = (const float*)d_in[2];
  const float* bias = (const float*)d_in[3];
  const float* log_alpha = (const float*)d_in[4];

  float* out = (float*)d_out;                               // outs region [T][B][D]
  float* hreg = out + (size_t)T_STEPS * BATCH * DIM;        // h region [T+1][B][D]
  __hip_bfloat16* xb = (__hip_bfloat16*)d_out;
  __hip_bfloat16* wb = (__hip_bfloat16*)((char*)d_out + (size_t)T_STEPS * BATCH * DIM * 2);
  float4* scal4 = (float4*)(out + (size_t)26 * 1024 * 1024);  // 104 MB offset
  float2* d45g = (float2*)(out + (size_t)27 * 1024 * 1024);   // 108 MB offset

  const int nx8 = T_STEPS * BATCH * DIM / 8;
  const int nw8 = DIM * DIM / 8;
  const int ntot8 = nx8 + nw8;
  cvt_kernel<<<(ntot8 + 255) / 256, 256, 0, stream>>>(x, W, (bf16x8pack*)xb,
                                                      (bf16x8pack*)wb, nx8, ntot8);

  gemm_kernel<<<512, 512, 0, stream>>>(xb, wb, bias, log_alpha, hreg);

  dots_kernel<<<(T_STEPS / 8) * BATCH, 64, 0, stream>>>(hreg, scal4, d45g);

  scan_kernel<<<BATCH, 256, 0, stream>>>(h0, scal4, d45g, hreg);

  const int n4 = T_STEPS * BATCH * DIM / 4;
  silu_kernel<<<2048, 256, 0, stream>>>((const float4*)(hreg + BATCH * DIM),
                                        (float4*)out, n4);
}